// Round 2
// baseline (1795.476 us; speedup 1.0000x reference)
//
#include <hip/hip_runtime.h>
#include <cstdint>

#define LOG2E 1.4426950408889634f
#define BCH 16                 // batches per chunk
#define RC  (BCH * 2048)       // rows per chunk = 32768

typedef __attribute__((ext_vector_type(8))) short short8;
typedef __attribute__((ext_vector_type(4))) float f32x4;

__device__ __forceinline__ float b2f(unsigned short u) {
  union { unsigned int u; float f; } c; c.u = ((unsigned int)u) << 16; return c.f;
}
__device__ __forceinline__ unsigned short f2b(float f) {
  union { float f; unsigned int u; } c; c.f = f;
  unsigned int r = c.u + 0x7FFFu + ((c.u >> 16) & 1u);
  return (unsigned short)(r >> 16);
}

// async global->LDS, 16B/lane; LDS dest contiguous in lane order (base+lane*16B)
__device__ __forceinline__ void gl2lds16(void* l, const void* g) {
  __builtin_amdgcn_global_load_lds(
      (const __attribute__((address_space(1))) void*)g,
      (__attribute__((address_space(3))) void*)l, 16, 0, 0);
}

// ---------------- weight prep: fp32 -> bf16, and AA = -exp(A_log)*log2e ----
__global__ __launch_bounds__(256) void prep_weights(
    const float* __restrict__ inw, const float* __restrict__ xw,
    const float* __restrict__ ow, const float* __restrict__ alog,
    unsigned short* __restrict__ inwb, unsigned short* __restrict__ xwb,
    unsigned short* __restrict__ owb, float* __restrict__ AA) {
  int gid = blockIdx.x * 256 + threadIdx.x;
  const int n_in = 2 * 1024 * 256;   // 524288
  const int n_x  = 2 * 48 * 512;     // 49152
  const int n_o  = 2 * 256 * 512;    // 262144
  const int n_a  = 2 * 512 * 16;     // 16384
  if (gid < n_in) { inwb[gid] = f2b(inw[gid]); return; }
  gid -= n_in;
  if (gid < n_x) { xwb[gid] = f2b(xw[gid]); return; }
  gid -= n_x;
  if (gid < n_o) { owb[gid] = f2b(ow[gid]); return; }
  gid -= n_o;
  if (gid < n_a) { AA[gid] = -__expf(alog[gid]) * LOG2E; }
}

// ---------------- x = x * mask ---------------------------------------------
__global__ __launch_bounds__(256) void mask_x(
    const float* __restrict__ x, const int* __restrict__ mask,
    float* __restrict__ X) {
  int gid = blockIdx.x * 256 + threadIdx.x;     // (b,t,d), d fastest (256)
  int row = gid >> 8;
  X[gid] = mask[row] ? x[gid] : 0.f;
}

// ---------------- LayerNorm: X fp32 -> XN bf16 (row = blockIdx) ------------
__global__ __launch_bounds__(256) void ln_fwd(
    const float* __restrict__ X, const float* __restrict__ w,
    const float* __restrict__ b, unsigned short* __restrict__ XN) {
  int row = blockIdx.x;
  int t = threadIdx.x;
  float v = X[(long)row * 256 + t];
  float s = v, s2 = v * v;
  #pragma unroll
  for (int o = 32; o > 0; o >>= 1) {
    s += __shfl_down(s, o, 64);
    s2 += __shfl_down(s2, o, 64);
  }
  __shared__ float rs[4], rs2[4];
  __shared__ float mu_s, rst_s;
  int wv = t >> 6, ln = t & 63;
  if (ln == 0) { rs[wv] = s; rs2[wv] = s2; }
  __syncthreads();
  if (t == 0) {
    float S = rs[0] + rs[1] + rs[2] + rs[3];
    float S2 = rs2[0] + rs2[1] + rs2[2] + rs2[3];
    float mu = S * (1.f / 256.f);
    float var = S2 * (1.f / 256.f) - mu * mu;
    mu_s = mu;
    rst_s = rsqrtf(var + 1e-5f);
  }
  __syncthreads();
  float xn = (v - mu_s) * rst_s * w[t] + b[t];
  XN[(long)row * 256 + t] = f2b(xn);
}

// ---------------- 128x128 bf16 MFMA GEMM, C = A(MxK) * B(NxK)^T ------------
// epi==0: split store bf16: col<512 -> OutU[row*512+col], else OutZ[row*512+col-512]
// epi==1: OutF[row*N+col] = Xres[row*N+col] + (mask[row] ? acc : 0)
__global__ __launch_bounds__(256) void gemm128(
    const unsigned short* __restrict__ A, const unsigned short* __restrict__ B,
    const float* __restrict__ Xres, unsigned short* __restrict__ OutU,
    unsigned short* __restrict__ OutZ, float* __restrict__ OutF,
    const int* __restrict__ mask, int N, int K, int epi) {
  __shared__ unsigned short As[128 * 32];
  __shared__ unsigned short Bs[128 * 32];
  const int tid = threadIdx.x;
  const int wave = tid >> 6, lane = tid & 63;
  const int m0 = blockIdx.x * 128, n0 = blockIdx.y * 128;
  const int wm = (wave >> 1) * 64, wn = (wave & 1) * 64;

  f32x4 acc[4][4];
  #pragma unroll
  for (int i = 0; i < 4; i++)
    #pragma unroll
    for (int j = 0; j < 4; j++)
      #pragma unroll
      for (int r = 0; r < 4; r++) acc[i][j][r] = 0.f;

  const int srow = wave * 32 + (lane >> 2);
  const int skcol = (lane & 3) * 8;
  unsigned short* AsW = &As[srow * 32 + skcol];
  unsigned short* BsW = &Bs[srow * 32 + skcol];
  const unsigned short* Ag = A + (long)(m0 + srow) * K + skcol;
  const unsigned short* Bg = B + (long)(n0 + srow) * K + skcol;

  const int fr = lane & 15, fk = (lane >> 4) * 8;

  for (int k0 = 0; k0 < K; k0 += 32) {
    gl2lds16(AsW,            Ag + k0);
    gl2lds16(AsW + 16 * 32,  Ag + (long)16 * K + k0);
    gl2lds16(BsW,            Bg + k0);
    gl2lds16(BsW + 16 * 32,  Bg + (long)16 * K + k0);
    __syncthreads();
    short8 af[4], bf[4];
    #pragma unroll
    for (int i = 0; i < 4; i++) {
      af[i] = *(const short8*)&As[(wm + i * 16 + fr) * 32 + fk];
      bf[i] = *(const short8*)&Bs[(wn + i * 16 + fr) * 32 + fk];
    }
    #pragma unroll
    for (int i = 0; i < 4; i++)
      #pragma unroll
      for (int j = 0; j < 4; j++)
        acc[i][j] = __builtin_amdgcn_mfma_f32_16x16x32_bf16(af[i], bf[j], acc[i][j], 0, 0, 0);
    __syncthreads();
  }

  const int cl = lane & 15, rq = (lane >> 4) * 4;
  #pragma unroll
  for (int i = 0; i < 4; i++)
    #pragma unroll
    for (int j = 0; j < 4; j++) {
      int col = n0 + wn + j * 16 + cl;
      #pragma unroll
      for (int r = 0; r < 4; r++) {
        int row = m0 + wm + i * 16 + rq + r;
        float v = acc[i][j][r];
        if (epi == 0) {
          if (col < 512) OutU[(long)row * 512 + col] = f2b(v);
          else           OutZ[(long)row * 512 + (col - 512)] = f2b(v);
        } else {
          long idx = (long)row * N + col;
          OutF[idx] = Xres[idx] + (mask[row] ? v : 0.f);
        }
      }
    }
}

// ---------------- 128x48 bf16 MFMA GEMM for x_proj (K=512), fp32 out -------
__global__ __launch_bounds__(256) void gemm_n48(
    const unsigned short* __restrict__ A, const unsigned short* __restrict__ B,
    float* __restrict__ Out, int K) {
  __shared__ unsigned short As[128 * 32];
  __shared__ unsigned short Bs[48 * 32];
  const int tid = threadIdx.x;
  const int wave = tid >> 6, lane = tid & 63;
  const int m0 = blockIdx.x * 128;
  const int wm = wave * 32;

  f32x4 acc[2][3];
  #pragma unroll
  for (int i = 0; i < 2; i++)
    #pragma unroll
    for (int j = 0; j < 3; j++)
      #pragma unroll
      for (int r = 0; r < 4; r++) acc[i][j][r] = 0.f;

  const int srow = wave * 32 + (lane >> 2);
  const int skcol = (lane & 3) * 8;
  unsigned short* AsW = &As[srow * 32 + skcol];
  const unsigned short* Ag = A + (long)(m0 + srow) * K + skcol;
  const int brow = wave * 16 + (lane >> 2);   // waves 0..2 stage rows 0..47
  unsigned short* BsW = &Bs[brow * 32 + skcol];
  const unsigned short* Bg = B + (long)brow * K + skcol;

  const int fr = lane & 15, fk = (lane >> 4) * 8;

  for (int k0 = 0; k0 < K; k0 += 32) {
    gl2lds16(AsW,           Ag + k0);
    gl2lds16(AsW + 16 * 32, Ag + (long)16 * K + k0);
    if (wave < 3) gl2lds16(BsW, Bg + k0);
    __syncthreads();
    short8 af[2], bf[3];
    #pragma unroll
    for (int i = 0; i < 2; i++)
      af[i] = *(const short8*)&As[(wm + i * 16 + fr) * 32 + fk];
    #pragma unroll
    for (int j = 0; j < 3; j++)
      bf[j] = *(const short8*)&Bs[(j * 16 + fr) * 32 + fk];
    #pragma unroll
    for (int i = 0; i < 2; i++)
      #pragma unroll
      for (int j = 0; j < 3; j++)
        acc[i][j] = __builtin_amdgcn_mfma_f32_16x16x32_bf16(af[i], bf[j], acc[i][j], 0, 0, 0);
    __syncthreads();
  }

  const int cl = lane & 15, rq = (lane >> 4) * 4;
  #pragma unroll
  for (int i = 0; i < 2; i++)
    #pragma unroll
    for (int j = 0; j < 3; j++) {
      int col = j * 16 + cl;
      #pragma unroll
      for (int r = 0; r < 4; r++) {
        int row = m0 + wm + i * 16 + rq + r;
        Out[(long)row * 48 + col] = acc[i][j][r];
      }
    }
}

// ---------------- causal depthwise conv(4) + silu: Upre -> U (bf16) --------
__global__ __launch_bounds__(256) void conv_silu(
    const unsigned short* __restrict__ Upre, const float* __restrict__ cw,
    const float* __restrict__ cb, unsigned short* __restrict__ U) {
  int gid = blockIdx.x * 256 + threadIdx.x;  // local (b,t,d) d fastest (512)
  int d = gid & 511;
  int row = gid >> 9;          // b*2048 + t (chunk-local)
  int t = row & 2047;
  float acc = cb[d];
  #pragma unroll
  for (int k = 0; k < 4; k++) {
    int tt = t + k - 3;
    if (tt >= 0)
      acc = fmaf(b2f(Upre[(long)(row + k - 3) * 512 + d]), cw[d * 4 + k], acc);
  }
  float sg = 1.f / (1.f + __expf(-acc));
  U[gid] = f2b(acc * sg);
}

// ---------------- scan pass 1: per-chunk end state + sum(dt) ---------------
// thread = (b, c, d); chunk length 32, 64 chunks, b chunk-local
__global__ __launch_bounds__(256) void scan_p1(
    const unsigned short* __restrict__ U, const float* __restrict__ XD,
    const float* __restrict__ AA, const float* __restrict__ dtw,
    const float* __restrict__ dtb, float* __restrict__ HCH,
    float* __restrict__ DTS) {
  int gid = blockIdx.x * 256 + threadIdx.x;
  int d = gid & 511;
  int bc = gid >> 9;
  int c = bc & 63, b = bc >> 6;
  float aa[16], wdt[16], h[16];
  #pragma unroll
  for (int n = 0; n < 16; n++) {
    aa[n] = AA[d * 16 + n];
    wdt[n] = dtw[d * 16 + n];
    h[n] = 0.f;
  }
  float bias = dtb[d];
  float dts = 0.f;
  long row0 = (long)b * 2048 + c * 32;
  for (int tt = 0; tt < 32; tt++) {
    long row = row0 + tt;
    const float* xd = &XD[row * 48];
    float s = bias;
    #pragma unroll
    for (int r = 0; r < 16; r++) s = fmaf(xd[r], wdt[r], s);
    float e = __expf(-fabsf(s));
    float dt = fmaxf(s, 0.f) + __logf(1.f + e);   // softplus
    float u = b2f(U[row * 512 + d]);
    float du = dt * u;
    const float* Bp = xd + 16;
    #pragma unroll
    for (int n = 0; n < 16; n++)
      h[n] = fmaf(exp2f(dt * aa[n]), h[n], du * Bp[n]);
    dts += dt;
  }
  long o = (long)gid * 16;
  #pragma unroll
  for (int n = 0; n < 16; n++) HCH[o + n] = h[n];
  DTS[gid] = dts;
}

// ---------------- scan pass 2: prefix over chunks (h_end -> h_start) -------
// thread = (b, d, n), b chunk-local
__global__ __launch_bounds__(256) void scan_p2(
    float* __restrict__ HCH, const float* __restrict__ DTS,
    const float* __restrict__ AA) {
  int gid = blockIdx.x * 256 + threadIdx.x;   // b*8192 + d*16 + n
  int n = gid & 15;
  int d = (gid >> 4) & 511;
  int b = gid >> 13;
  float aa = AA[d * 16 + n];
  float hrun = 0.f;
  for (int c = 0; c < 64; c++) {
    long base = ((long)b * 64 + c) * 512 + d;
    long idx = base * 16 + n;
    float hend = HCH[idx];
    float P = exp2f(DTS[base] * aa);
    HCH[idx] = hrun;            // becomes h_start for chunk c
    hrun = fmaf(P, hrun, hend);
  }
}

// ---------------- scan pass 3: replay with h_start, fused gate -------------
// Y may alias U (each thread reads U[row*512+d] before writing same element)
__global__ __launch_bounds__(256) void scan_p3(
    const unsigned short* __restrict__ U, const unsigned short* __restrict__ Z,
    const float* __restrict__ XD, const float* __restrict__ AA,
    const float* __restrict__ dtw, const float* __restrict__ dtb,
    const float* __restrict__ HCH, const float* __restrict__ skD,
    unsigned short* __restrict__ Y) {
  int gid = blockIdx.x * 256 + threadIdx.x;
  int d = gid & 511;
  int bc = gid >> 9;
  int c = bc & 63, b = bc >> 6;
  float aa[16], wdt[16], h[16];
  long o = (long)gid * 16;
  #pragma unroll
  for (int n = 0; n < 16; n++) {
    aa[n] = AA[d * 16 + n];
    wdt[n] = dtw[d * 16 + n];
    h[n] = HCH[o + n];
  }
  float bias = dtb[d];
  float sD = skD[d];
  long row0 = (long)b * 2048 + c * 32;
  for (int tt = 0; tt < 32; tt++) {
    long row = row0 + tt;
    const float* xd = &XD[row * 48];
    float s = bias;
    #pragma unroll
    for (int r = 0; r < 16; r++) s = fmaf(xd[r], wdt[r], s);
    float e = __expf(-fabsf(s));
    float dt = fmaxf(s, 0.f) + __logf(1.f + e);
    float u = b2f(U[row * 512 + d]);
    float du = dt * u;
    const float* Bp = xd + 16;
    const float* Cp = xd + 32;
    float y = 0.f;
    #pragma unroll
    for (int n = 0; n < 16; n++) {
      h[n] = fmaf(exp2f(dt * aa[n]), h[n], du * Bp[n]);
      y = fmaf(h[n], Cp[n], y);
    }
    y = fmaf(u, sD, y);
    float z = b2f(Z[row * 512 + d]);
    float sg = z / (1.f + __expf(-z));      // silu(z)
    Y[row * 512 + d] = f2b(y * sg);
  }
}

extern "C" void kernel_launch(void* const* d_in, const int* in_sizes, int n_in,
                              void* d_out, int out_size, void* d_ws, size_t ws_size,
                              hipStream_t stream) {
  const float* x        = (const float*)d_in[0];
  const int*   mask     = (const int*)d_in[1];
  const float* ln_w     = (const float*)d_in[2];
  const float* ln_b     = (const float*)d_in[3];
  const float* in_proj  = (const float*)d_in[4];
  const float* conv_w   = (const float*)d_in[5];
  const float* conv_b   = (const float*)d_in[6];
  const float* x_proj   = (const float*)d_in[7];
  const float* dt_w     = (const float*)d_in[8];
  const float* dt_b     = (const float*)d_in[9];
  const float* A_log    = (const float*)d_in[10];
  const float* skip_D   = (const float*)d_in[11];
  const float* out_proj = (const float*)d_in[12];
  float* X = (float*)d_out;

  // ---- workspace layout (~114 MB total) ----
  char* p = (char*)d_ws;
  auto alloc = [&](size_t n) { char* r = p; p += (n + 255) & ~(size_t)255; return r; };
  unsigned short* WBin  = (unsigned short*)alloc((size_t)2 * 1024 * 256 * 2);  // 1 MB
  unsigned short* WBx   = (unsigned short*)alloc((size_t)2 * 48 * 512 * 2);
  unsigned short* WBout = (unsigned short*)alloc((size_t)2 * 256 * 512 * 2);
  float*          AA    = (float*)alloc((size_t)2 * 512 * 16 * 4);
  char* R_XN   = alloc((size_t)RC * 256 * 2);        // 16 MB: XN, then XD+DTS
  char* R_UPRE = alloc((size_t)RC * 512 * 2);        // 32 MB: Upre, then HCH
  char* R_Z    = alloc((size_t)RC * 512 * 2);        // 32 MB: Z
  char* R_U    = alloc((size_t)RC * 512 * 2);        // 32 MB: U (=Y in-place)

  unsigned short* XN   = (unsigned short*)R_XN;
  float*          XD   = (float*)R_XN;                         // after in_proj
  float*          DTS  = (float*)(R_XN + 8388608);             // 2 MB @ +8 MB
  unsigned short* Upre = (unsigned short*)R_UPRE;
  float*          HCH  = (float*)R_UPRE;                       // after conv
  unsigned short* Z    = (unsigned short*)R_Z;
  unsigned short* U    = (unsigned short*)R_U;

  prep_weights<<<3328, 256, 0, stream>>>(in_proj, x_proj, out_proj, A_log,
                                         WBin, WBx, WBout, AA);
  mask_x<<<65536, 256, 0, stream>>>(x, mask, X);

  for (int ch = 0; ch < 2; ch++) {
    const long row0 = (long)ch * RC;
    float* Xc = X + row0 * 256;
    const int* maskc = mask + row0;
    for (int i = 0; i < 2; i++) {
      ln_fwd<<<RC, 256, 0, stream>>>(Xc, ln_w + i * 256, ln_b + i * 256, XN);
      gemm128<<<dim3(RC / 128, 8), 256, 0, stream>>>(XN, WBin + i * 262144,
          nullptr, Upre, Z, nullptr, nullptr, 1024, 256, 0);
      conv_silu<<<RC * 2, 256, 0, stream>>>(Upre, conv_w + i * 2048,
          conv_b + i * 512, U);
      gemm_n48<<<RC / 128, 256, 0, stream>>>(U, WBx + i * 24576, XD, 512);
      scan_p1<<<BCH * 128, 256, 0, stream>>>(U, XD, AA + i * 8192,
          dt_w + i * 8192, dt_b + i * 512, HCH, DTS);
      scan_p2<<<BCH * 32, 256, 0, stream>>>(HCH, DTS, AA + i * 8192);
      scan_p3<<<BCH * 128, 256, 0, stream>>>(U, Z, XD, AA + i * 8192,
          dt_w + i * 8192, dt_b + i * 512, HCH, skip_D + i * 512, U);
      gemm128<<<dim3(RC / 128, 2), 256, 0, stream>>>(U, WBout + i * 131072,
          Xc, nullptr, nullptr, Xc, maskc, 256, 512, 1);
    }
  }
}

// Round 3
// 1667.888 us; speedup vs baseline: 1.0765x; 1.0765x over previous
//
#include <hip/hip_runtime.h>
#include <cstdint>

#define LOG2E 1.4426950408889634f
#define BCH 16                 // batches per chunk
#define RC  (BCH * 2048)       // rows per chunk = 32768

typedef __attribute__((ext_vector_type(8))) short short8;
typedef __attribute__((ext_vector_type(4))) float f32x4;
typedef __attribute__((ext_vector_type(4))) unsigned short ush4;

__device__ __forceinline__ float b2f(unsigned short u) {
  union { unsigned int u; float f; } c; c.u = ((unsigned int)u) << 16; return c.f;
}
__device__ __forceinline__ unsigned short f2b(float f) {
  union { float f; unsigned int u; } c; c.f = f;
  unsigned int r = c.u + 0x7FFFu + ((c.u >> 16) & 1u);
  return (unsigned short)(r >> 16);
}
__device__ __forceinline__ f32x4 exp2v(f32x4 v) {
  f32x4 r; r.x = exp2f(v.x); r.y = exp2f(v.y); r.z = exp2f(v.z); r.w = exp2f(v.w);
  return r;
}

// async global->LDS, 16B/lane; LDS dest contiguous in lane order (base+lane*16B)
__device__ __forceinline__ void gl2lds16(void* l, const void* g) {
  __builtin_amdgcn_global_load_lds(
      (const __attribute__((address_space(1))) void*)g,
      (__attribute__((address_space(3))) void*)l, 16, 0, 0);
}

// ---------------- weight prep: fp32 -> bf16, and AA = -exp(A_log)*log2e ----
__global__ __launch_bounds__(256) void prep_weights(
    const float* __restrict__ inw, const float* __restrict__ xw,
    const float* __restrict__ ow, const float* __restrict__ alog,
    unsigned short* __restrict__ inwb, unsigned short* __restrict__ xwb,
    unsigned short* __restrict__ owb, float* __restrict__ AA) {
  int gid = blockIdx.x * 256 + threadIdx.x;
  const int n_in = 2 * 1024 * 256;   // 524288
  const int n_x  = 2 * 48 * 512;     // 49152
  const int n_o  = 2 * 256 * 512;    // 262144
  const int n_a  = 2 * 512 * 16;     // 16384
  if (gid < n_in) { inwb[gid] = f2b(inw[gid]); return; }
  gid -= n_in;
  if (gid < n_x) { xwb[gid] = f2b(xw[gid]); return; }
  gid -= n_x;
  if (gid < n_o) { owb[gid] = f2b(ow[gid]); return; }
  gid -= n_o;
  if (gid < n_a) { AA[gid] = -__expf(alog[gid]) * LOG2E; }
}

// ---------------- x = x * mask ---------------------------------------------
__global__ __launch_bounds__(256) void mask_x(
    const float* __restrict__ x, const int* __restrict__ mask,
    float* __restrict__ X) {
  int gid = blockIdx.x * 256 + threadIdx.x;     // (b,t,d), d fastest (256)
  int row = gid >> 8;
  X[gid] = mask[row] ? x[gid] : 0.f;
}

// ---------------- LayerNorm: one wave per row, X fp32 -> XN bf16 -----------
__global__ __launch_bounds__(256) void ln_fwd(
    const float* __restrict__ X, const float* __restrict__ w,
    const float* __restrict__ b, unsigned short* __restrict__ XN) {
  int wv = threadIdx.x >> 6, ln = threadIdx.x & 63;
  long row = (long)blockIdx.x * 4 + wv;
  f32x4 v = ((const f32x4*)(X + row * 256))[ln];
  float s = v.x + v.y + v.z + v.w;
  float s2 = v.x * v.x + v.y * v.y + v.z * v.z + v.w * v.w;
  #pragma unroll
  for (int o = 32; o > 0; o >>= 1) {
    s += __shfl_xor(s, o, 64);
    s2 += __shfl_xor(s2, o, 64);
  }
  float mu = s * (1.f / 256.f);
  float var = s2 * (1.f / 256.f) - mu * mu;
  float rst = rsqrtf(var + 1e-5f);
  f32x4 wv4 = ((const f32x4*)w)[ln];
  f32x4 bv4 = ((const f32x4*)b)[ln];
  ush4 o4;
  o4.x = f2b((v.x - mu) * rst * wv4.x + bv4.x);
  o4.y = f2b((v.y - mu) * rst * wv4.y + bv4.y);
  o4.z = f2b((v.z - mu) * rst * wv4.z + bv4.z);
  o4.w = f2b((v.w - mu) * rst * wv4.w + bv4.w);
  ((ush4*)(XN + row * 256))[ln] = o4;
}

// ---------------- 128x128 bf16 MFMA GEMM, C = A(MxK) * B(NxK)^T ------------
// epi==0: split store bf16: col<512 -> OutU, else OutZ
// epi==1: OutF[row*N+col] = Xres[row*N+col] + (mask[row] ? acc : 0)
__global__ __launch_bounds__(256) void gemm128(
    const unsigned short* __restrict__ A, const unsigned short* __restrict__ B,
    const float* __restrict__ Xres, unsigned short* __restrict__ OutU,
    unsigned short* __restrict__ OutZ, float* __restrict__ OutF,
    const int* __restrict__ mask, int N, int K, int epi) {
  __shared__ unsigned short As[128 * 32];
  __shared__ unsigned short Bs[128 * 32];
  const int tid = threadIdx.x;
  const int wave = tid >> 6, lane = tid & 63;
  const int m0 = blockIdx.x * 128, n0 = blockIdx.y * 128;
  const int wm = (wave >> 1) * 64, wn = (wave & 1) * 64;

  f32x4 acc[4][4];
  #pragma unroll
  for (int i = 0; i < 4; i++)
    #pragma unroll
    for (int j = 0; j < 4; j++)
      #pragma unroll
      for (int r = 0; r < 4; r++) acc[i][j][r] = 0.f;

  const int srow = wave * 32 + (lane >> 2);
  const int skcol = (lane & 3) * 8;
  unsigned short* AsW = &As[srow * 32 + skcol];
  unsigned short* BsW = &Bs[srow * 32 + skcol];
  const unsigned short* Ag = A + (long)(m0 + srow) * K + skcol;
  const unsigned short* Bg = B + (long)(n0 + srow) * K + skcol;

  const int fr = lane & 15, fk = (lane >> 4) * 8;

  for (int k0 = 0; k0 < K; k0 += 32) {
    gl2lds16(AsW,            Ag + k0);
    gl2lds16(AsW + 16 * 32,  Ag + (long)16 * K + k0);
    gl2lds16(BsW,            Bg + k0);
    gl2lds16(BsW + 16 * 32,  Bg + (long)16 * K + k0);
    __syncthreads();
    short8 af[4], bf[4];
    #pragma unroll
    for (int i = 0; i < 4; i++) {
      af[i] = *(const short8*)&As[(wm + i * 16 + fr) * 32 + fk];
      bf[i] = *(const short8*)&Bs[(wn + i * 16 + fr) * 32 + fk];
    }
    #pragma unroll
    for (int i = 0; i < 4; i++)
      #pragma unroll
      for (int j = 0; j < 4; j++)
        acc[i][j] = __builtin_amdgcn_mfma_f32_16x16x32_bf16(af[i], bf[j], acc[i][j], 0, 0, 0);
    __syncthreads();
  }

  const int cl = lane & 15, rq = (lane >> 4) * 4;
  #pragma unroll
  for (int i = 0; i < 4; i++)
    #pragma unroll
    for (int j = 0; j < 4; j++) {
      int col = n0 + wn + j * 16 + cl;
      #pragma unroll
      for (int r = 0; r < 4; r++) {
        int row = m0 + wm + i * 16 + rq + r;
        float v = acc[i][j][r];
        if (epi == 0) {
          if (col < 512) OutU[(long)row * 512 + col] = f2b(v);
          else           OutZ[(long)row * 512 + (col - 512)] = f2b(v);
        } else {
          long idx = (long)row * N + col;
          OutF[idx] = Xres[idx] + (mask[row] ? v : 0.f);
        }
      }
    }
}

// ---------------- 128x48 bf16 MFMA GEMM for x_proj (K=512), fp32 out -------
__global__ __launch_bounds__(256) void gemm_n48(
    const unsigned short* __restrict__ A, const unsigned short* __restrict__ B,
    float* __restrict__ Out, int K) {
  __shared__ unsigned short As[128 * 32];
  __shared__ unsigned short Bs[48 * 32];
  const int tid = threadIdx.x;
  const int wave = tid >> 6, lane = tid & 63;
  const int m0 = blockIdx.x * 128;
  const int wm = wave * 32;

  f32x4 acc[2][3];
  #pragma unroll
  for (int i = 0; i < 2; i++)
    #pragma unroll
    for (int j = 0; j < 3; j++)
      #pragma unroll
      for (int r = 0; r < 4; r++) acc[i][j][r] = 0.f;

  const int srow = wave * 32 + (lane >> 2);
  const int skcol = (lane & 3) * 8;
  unsigned short* AsW = &As[srow * 32 + skcol];
  const unsigned short* Ag = A + (long)(m0 + srow) * K + skcol;
  const int brow = wave * 16 + (lane >> 2);   // waves 0..2 stage rows 0..47
  unsigned short* BsW = &Bs[brow * 32 + skcol];
  const unsigned short* Bg = B + (long)brow * K + skcol;

  const int fr = lane & 15, fk = (lane >> 4) * 8;

  for (int k0 = 0; k0 < K; k0 += 32) {
    gl2lds16(AsW,           Ag + k0);
    gl2lds16(AsW + 16 * 32, Ag + (long)16 * K + k0);
    if (wave < 3) gl2lds16(BsW, Bg + k0);
    __syncthreads();
    short8 af[2], bf[3];
    #pragma unroll
    for (int i = 0; i < 2; i++)
      af[i] = *(const short8*)&As[(wm + i * 16 + fr) * 32 + fk];
    #pragma unroll
    for (int j = 0; j < 3; j++)
      bf[j] = *(const short8*)&Bs[(j * 16 + fr) * 32 + fk];
    #pragma unroll
    for (int i = 0; i < 2; i++)
      #pragma unroll
      for (int j = 0; j < 3; j++)
        acc[i][j] = __builtin_amdgcn_mfma_f32_16x16x32_bf16(af[i], bf[j], acc[i][j], 0, 0, 0);
    __syncthreads();
  }

  const int cl = lane & 15, rq = (lane >> 4) * 4;
  #pragma unroll
  for (int i = 0; i < 2; i++)
    #pragma unroll
    for (int j = 0; j < 3; j++) {
      int col = j * 16 + cl;
      #pragma unroll
      for (int r = 0; r < 4; r++) {
        int row = m0 + wm + i * 16 + rq + r;
        Out[(long)row * 48 + col] = acc[i][j][r];
      }
    }
}

// ---------------- causal depthwise conv(4) + silu: Upre -> U (bf16) --------
__global__ __launch_bounds__(256) void conv_silu(
    const unsigned short* __restrict__ Upre, const float* __restrict__ cw,
    const float* __restrict__ cb, unsigned short* __restrict__ U) {
  int gid = blockIdx.x * 256 + threadIdx.x;  // local (b,t,d) d fastest (512)
  int d = gid & 511;
  int row = gid >> 9;          // b*2048 + t (chunk-local)
  int t = row & 2047;
  float acc = cb[d];
  #pragma unroll
  for (int k = 0; k < 4; k++) {
    int tt = t + k - 3;
    if (tt >= 0)
      acc = fmaf(b2f(Upre[(long)(row + k - 3) * 512 + d]), cw[d * 4 + k], acc);
  }
  float sg = 1.f / (1.f + __expf(-acc));
  U[gid] = f2b(acc * sg);
}

// ---------------- scan pass 1: per-chunk end state + sum(dt) ---------------
// thread = (b, c, d); chunk length 32, 64 chunks, b chunk-local
__global__ __launch_bounds__(256) void scan_p1(
    const unsigned short* __restrict__ U, const float* __restrict__ XD,
    const float* __restrict__ AA, const float* __restrict__ dtw,
    const float* __restrict__ dtb, float* __restrict__ HCH,
    float* __restrict__ DTS) {
  int gid = blockIdx.x * 256 + threadIdx.x;
  int d = gid & 511;
  int bc = gid >> 9;
  int c = bc & 63, b = bc >> 6;
  const f32x4* aap = (const f32x4*)(AA + d * 16);
  const f32x4* wdp = (const f32x4*)(dtw + d * 16);
  f32x4 aa0 = aap[0], aa1 = aap[1], aa2 = aap[2], aa3 = aap[3];
  f32x4 w0 = wdp[0], w1 = wdp[1], w2 = wdp[2], w3 = wdp[3];
  f32x4 h0 = {0.f,0.f,0.f,0.f}, h1 = h0, h2 = h0, h3 = h0;
  float bias = dtb[d];
  float dts = 0.f;
  int row = b * 2048 + c * 32;
  const unsigned short* Up = U + (long)row * 512 + d;
  for (int tt = 0; tt < 32; tt++, row++, Up += 512) {
    // XD row is wave-uniform: force scalar loads
    int off = __builtin_amdgcn_readfirstlane(row * 48);
    const f32x4* xs = (const f32x4*)(XD + off);
    f32x4 x0 = xs[0], x1 = xs[1], x2 = xs[2], x3 = xs[3];   // dt_in
    f32x4 B0 = xs[4], B1 = xs[5], B2 = xs[6], B3 = xs[7];   // B
    f32x4 pp = x0 * w0 + x1 * w1 + x2 * w2 + x3 * w3;
    float s = bias + pp.x + pp.y + pp.z + pp.w;
    float e = __expf(-fabsf(s));
    float dt = fmaxf(s, 0.f) + __logf(1.f + e);   // softplus
    float du = dt * b2f(*Up);
    h0 = exp2v(dt * aa0) * h0 + du * B0;
    h1 = exp2v(dt * aa1) * h1 + du * B1;
    h2 = exp2v(dt * aa2) * h2 + du * B2;
    h3 = exp2v(dt * aa3) * h3 + du * B3;
    dts += dt;
  }
  f32x4* hp = (f32x4*)(HCH + (long)gid * 16);
  hp[0] = h0; hp[1] = h1; hp[2] = h2; hp[3] = h3;
  DTS[gid] = dts;
}

// ---------------- scan pass 2: prefix over chunks (h_end -> h_start) -------
// thread = (b, d, n), b chunk-local
__global__ __launch_bounds__(256) void scan_p2(
    float* __restrict__ HCH, const float* __restrict__ DTS,
    const float* __restrict__ AA) {
  int gid = blockIdx.x * 256 + threadIdx.x;   // b*8192 + d*16 + n
  int n = gid & 15;
  int d = (gid >> 4) & 511;
  int b = gid >> 13;
  float aa = AA[d * 16 + n];
  float hrun = 0.f;
  for (int c = 0; c < 64; c++) {
    long base = ((long)b * 64 + c) * 512 + d;
    long idx = base * 16 + n;
    float hend = HCH[idx];
    float P = exp2f(DTS[base] * aa);
    HCH[idx] = hrun;            // becomes h_start for chunk c
    hrun = fmaf(P, hrun, hend);
  }
}

// ---------------- scan pass 3: replay with h_start, fused gate -------------
// Y may alias U (same-thread same-element read-before-write)
__global__ __launch_bounds__(256) void scan_p3(
    const unsigned short* __restrict__ U, const unsigned short* __restrict__ Z,
    const float* __restrict__ XD, const float* __restrict__ AA,
    const float* __restrict__ dtw, const float* __restrict__ dtb,
    const float* __restrict__ HCH, const float* __restrict__ skD,
    unsigned short* __restrict__ Y) {
  int gid = blockIdx.x * 256 + threadIdx.x;
  int d = gid & 511;
  int bc = gid >> 9;
  int c = bc & 63, b = bc >> 6;
  const f32x4* aap = (const f32x4*)(AA + d * 16);
  const f32x4* wdp = (const f32x4*)(dtw + d * 16);
  f32x4 aa0 = aap[0], aa1 = aap[1], aa2 = aap[2], aa3 = aap[3];
  f32x4 w0 = wdp[0], w1 = wdp[1], w2 = wdp[2], w3 = wdp[3];
  const f32x4* hp = (const f32x4*)(HCH + (long)gid * 16);
  f32x4 h0 = hp[0], h1 = hp[1], h2 = hp[2], h3 = hp[3];
  float bias = dtb[d];
  float sD = skD[d];
  int row = b * 2048 + c * 32;
  const unsigned short* Up = U + (long)row * 512 + d;
  const unsigned short* Zp = Z + (long)row * 512 + d;
  unsigned short* Yp = Y + (long)row * 512 + d;
  for (int tt = 0; tt < 32; tt++, row++, Up += 512, Zp += 512, Yp += 512) {
    int off = __builtin_amdgcn_readfirstlane(row * 48);
    const f32x4* xs = (const f32x4*)(XD + off);
    f32x4 x0 = xs[0], x1 = xs[1], x2 = xs[2], x3 = xs[3];   // dt_in
    f32x4 B0 = xs[4], B1 = xs[5], B2 = xs[6], B3 = xs[7];   // B
    f32x4 C0 = xs[8], C1 = xs[9], C2 = xs[10], C3 = xs[11]; // C
    f32x4 pp = x0 * w0 + x1 * w1 + x2 * w2 + x3 * w3;
    float s = bias + pp.x + pp.y + pp.z + pp.w;
    float e = __expf(-fabsf(s));
    float dt = fmaxf(s, 0.f) + __logf(1.f + e);
    float u = b2f(*Up);
    float du = dt * u;
    h0 = exp2v(dt * aa0) * h0 + du * B0;
    h1 = exp2v(dt * aa1) * h1 + du * B1;
    h2 = exp2v(dt * aa2) * h2 + du * B2;
    h3 = exp2v(dt * aa3) * h3 + du * B3;
    f32x4 yv = h0 * C0 + h1 * C1 + h2 * C2 + h3 * C3;
    float y = yv.x + yv.y + yv.z + yv.w + u * sD;
    float z = b2f(*Zp);
    float sg = z / (1.f + __expf(-z));      // silu(z)
    *Yp = f2b(y * sg);
  }
}

extern "C" void kernel_launch(void* const* d_in, const int* in_sizes, int n_in,
                              void* d_out, int out_size, void* d_ws, size_t ws_size,
                              hipStream_t stream) {
  const float* x        = (const float*)d_in[0];
  const int*   mask     = (const int*)d_in[1];
  const float* ln_w     = (const float*)d_in[2];
  const float* ln_b     = (const float*)d_in[3];
  const float* in_proj  = (const float*)d_in[4];
  const float* conv_w   = (const float*)d_in[5];
  const float* conv_b   = (const float*)d_in[6];
  const float* x_proj   = (const float*)d_in[7];
  const float* dt_w     = (const float*)d_in[8];
  const float* dt_b     = (const float*)d_in[9];
  const float* A_log    = (const float*)d_in[10];
  const float* skip_D   = (const float*)d_in[11];
  const float* out_proj = (const float*)d_in[12];
  float* X = (float*)d_out;

  // ---- workspace layout (~114 MB total) ----
  char* p = (char*)d_ws;
  auto alloc = [&](size_t n) { char* r = p; p += (n + 255) & ~(size_t)255; return r; };
  unsigned short* WBin  = (unsigned short*)alloc((size_t)2 * 1024 * 256 * 2);  // 1 MB
  unsigned short* WBx   = (unsigned short*)alloc((size_t)2 * 48 * 512 * 2);
  unsigned short* WBout = (unsigned short*)alloc((size_t)2 * 256 * 512 * 2);
  float*          AA    = (float*)alloc((size_t)2 * 512 * 16 * 4);
  char* R_XN   = alloc((size_t)RC * 256 * 2);        // 16 MB: XN, then XD+DTS
  char* R_UPRE = alloc((size_t)RC * 512 * 2);        // 32 MB: Upre, then HCH
  char* R_Z    = alloc((size_t)RC * 512 * 2);        // 32 MB: Z
  char* R_U    = alloc((size_t)RC * 512 * 2);        // 32 MB: U (=Y in-place)

  unsigned short* XN   = (unsigned short*)R_XN;
  float*          XD   = (float*)R_XN;                         // after in_proj
  float*          DTS  = (float*)(R_XN + 8388608);             // 2 MB @ +8 MB
  unsigned short* Upre = (unsigned short*)R_UPRE;
  float*          HCH  = (float*)R_UPRE;                       // after conv
  unsigned short* Z    = (unsigned short*)R_Z;
  unsigned short* U    = (unsigned short*)R_U;

  prep_weights<<<3328, 256, 0, stream>>>(in_proj, x_proj, out_proj, A_log,
                                         WBin, WBx, WBout, AA);
  mask_x<<<65536, 256, 0, stream>>>(x, mask, X);

  for (int ch = 0; ch < 2; ch++) {
    const long row0 = (long)ch * RC;
    float* Xc = X + row0 * 256;
    const int* maskc = mask + row0;
    for (int i = 0; i < 2; i++) {
      ln_fwd<<<RC / 4, 256, 0, stream>>>(Xc, ln_w + i * 256, ln_b + i * 256, XN);
      gemm128<<<dim3(RC / 128, 8), 256, 0, stream>>>(XN, WBin + i * 262144,
          nullptr, Upre, Z, nullptr, nullptr, 1024, 256, 0);
      conv_silu<<<RC * 2, 256, 0, stream>>>(Upre, conv_w + i * 2048,
          conv_b + i * 512, U);
      gemm_n48<<<RC / 128, 256, 0, stream>>>(U, WBx + i * 24576, XD, 512);
      scan_p1<<<BCH * 128, 256, 0, stream>>>(U, XD, AA + i * 8192,
          dt_w + i * 8192, dt_b + i * 512, HCH, DTS);
      scan_p2<<<BCH * 32, 256, 0, stream>>>(HCH, DTS, AA + i * 8192);
      scan_p3<<<BCH * 128, 256, 0, stream>>>(U, Z, XD, AA + i * 8192,
          dt_w + i * 8192, dt_b + i * 512, HCH, skip_D + i * 512, U);
      gemm128<<<dim3(RC / 128, 2), 256, 0, stream>>>(U, WBout + i * 131072,
          Xc, nullptr, nullptr, Xc, maskc, 256, 512, 1);
    }
  }
}

// Round 4
// 1667.881 us; speedup vs baseline: 1.0765x; 1.0000x over previous
//
#include <hip/hip_runtime.h>
#include <cstdint>

#define LOG2E 1.4426950408889634f
#define BCH 16                 // batches per chunk
#define RC  (BCH * 2048)       // rows per chunk = 32768

typedef __attribute__((ext_vector_type(8))) short short8;
typedef __attribute__((ext_vector_type(4))) float f32x4;
typedef __attribute__((ext_vector_type(4))) unsigned short ush4;

__device__ __forceinline__ float b2f(unsigned short u) {
  union { unsigned int u; float f; } c; c.u = ((unsigned int)u) << 16; return c.f;
}
__device__ __forceinline__ unsigned short f2b(float f) {
  union { float f; unsigned int u; } c; c.f = f;
  unsigned int r = c.u + 0x7FFFu + ((c.u >> 16) & 1u);
  return (unsigned short)(r >> 16);
}
__device__ __forceinline__ f32x4 exp2v(f32x4 v) {
  f32x4 r; r.x = exp2f(v.x); r.y = exp2f(v.y); r.z = exp2f(v.z); r.w = exp2f(v.w);
  return r;
}

// async global->LDS, 16B/lane; LDS dest contiguous in lane order (base+lane*16B)
__device__ __forceinline__ void gl2lds16(void* l, const void* g) {
  __builtin_amdgcn_global_load_lds(
      (const __attribute__((address_space(1))) void*)g,
      (__attribute__((address_space(3))) void*)l, 16, 0, 0);
}

// ---------------- weight prep: fp32 -> bf16, and AA = -exp(A_log)*log2e ----
__global__ __launch_bounds__(256) void prep_weights(
    const float* __restrict__ inw, const float* __restrict__ xw,
    const float* __restrict__ ow, const float* __restrict__ alog,
    unsigned short* __restrict__ inwb, unsigned short* __restrict__ xwb,
    unsigned short* __restrict__ owb, float* __restrict__ AA) {
  int gid = blockIdx.x * 256 + threadIdx.x;
  const int n_in = 2 * 1024 * 256;   // 524288
  const int n_x  = 2 * 48 * 512;     // 49152
  const int n_o  = 2 * 256 * 512;    // 262144
  const int n_a  = 2 * 512 * 16;     // 16384
  if (gid < n_in) { inwb[gid] = f2b(inw[gid]); return; }
  gid -= n_in;
  if (gid < n_x) { xwb[gid] = f2b(xw[gid]); return; }
  gid -= n_x;
  if (gid < n_o) { owb[gid] = f2b(ow[gid]); return; }
  gid -= n_o;
  if (gid < n_a) { AA[gid] = -__expf(alog[gid]) * LOG2E; }
}

// ---------------- x = x * mask ---------------------------------------------
__global__ __launch_bounds__(256) void mask_x(
    const float* __restrict__ x, const int* __restrict__ mask,
    float* __restrict__ X) {
  int gid = blockIdx.x * 256 + threadIdx.x;     // (b,t,d), d fastest (256)
  int row = gid >> 8;
  X[gid] = mask[row] ? x[gid] : 0.f;
}

// ---------------- LayerNorm: one wave per row, X fp32 -> XN bf16 -----------
__global__ __launch_bounds__(256) void ln_fwd(
    const float* __restrict__ X, const float* __restrict__ w,
    const float* __restrict__ b, unsigned short* __restrict__ XN) {
  int wv = threadIdx.x >> 6, ln = threadIdx.x & 63;
  long row = (long)blockIdx.x * 4 + wv;
  f32x4 v = ((const f32x4*)(X + row * 256))[ln];
  float s = v.x + v.y + v.z + v.w;
  float s2 = v.x * v.x + v.y * v.y + v.z * v.z + v.w * v.w;
  #pragma unroll
  for (int o = 32; o > 0; o >>= 1) {
    s += __shfl_xor(s, o, 64);
    s2 += __shfl_xor(s2, o, 64);
  }
  float mu = s * (1.f / 256.f);
  float var = s2 * (1.f / 256.f) - mu * mu;
  float rst = rsqrtf(var + 1e-5f);
  f32x4 wv4 = ((const f32x4*)w)[ln];
  f32x4 bv4 = ((const f32x4*)b)[ln];
  ush4 o4;
  o4.x = f2b((v.x - mu) * rst * wv4.x + bv4.x);
  o4.y = f2b((v.y - mu) * rst * wv4.y + bv4.y);
  o4.z = f2b((v.z - mu) * rst * wv4.z + bv4.z);
  o4.w = f2b((v.w - mu) * rst * wv4.w + bv4.w);
  ((ush4*)(XN + row * 256))[ln] = o4;
}

// ---------------- 128x128 bf16 MFMA GEMM, C = A(MxK) * B(NxK)^T ------------
// epi==0: split store bf16: col<512 -> OutU, else OutZ
// epi==1: OutF[row*N+col] = Xres[row*N+col] + (mask[row] ? acc : 0)
__global__ __launch_bounds__(256) void gemm128(
    const unsigned short* __restrict__ A, const unsigned short* __restrict__ B,
    const float* __restrict__ Xres, unsigned short* __restrict__ OutU,
    unsigned short* __restrict__ OutZ, float* __restrict__ OutF,
    const int* __restrict__ mask, int N, int K, int epi) {
  __shared__ unsigned short As[128 * 32];
  __shared__ unsigned short Bs[128 * 32];
  const int tid = threadIdx.x;
  const int wave = tid >> 6, lane = tid & 63;
  const int m0 = blockIdx.x * 128, n0 = blockIdx.y * 128;
  const int wm = (wave >> 1) * 64, wn = (wave & 1) * 64;

  f32x4 acc[4][4];
  #pragma unroll
  for (int i = 0; i < 4; i++)
    #pragma unroll
    for (int j = 0; j < 4; j++)
      #pragma unroll
      for (int r = 0; r < 4; r++) acc[i][j][r] = 0.f;

  const int srow = wave * 32 + (lane >> 2);
  const int skcol = (lane & 3) * 8;
  unsigned short* AsW = &As[srow * 32 + skcol];
  unsigned short* BsW = &Bs[srow * 32 + skcol];
  const unsigned short* Ag = A + (long)(m0 + srow) * K + skcol;
  const unsigned short* Bg = B + (long)(n0 + srow) * K + skcol;

  const int fr = lane & 15, fk = (lane >> 4) * 8;

  for (int k0 = 0; k0 < K; k0 += 32) {
    gl2lds16(AsW,            Ag + k0);
    gl2lds16(AsW + 16 * 32,  Ag + (long)16 * K + k0);
    gl2lds16(BsW,            Bg + k0);
    gl2lds16(BsW + 16 * 32,  Bg + (long)16 * K + k0);
    __syncthreads();
    short8 af[4], bf[4];
    #pragma unroll
    for (int i = 0; i < 4; i++) {
      af[i] = *(const short8*)&As[(wm + i * 16 + fr) * 32 + fk];
      bf[i] = *(const short8*)&Bs[(wn + i * 16 + fr) * 32 + fk];
    }
    #pragma unroll
    for (int i = 0; i < 4; i++)
      #pragma unroll
      for (int j = 0; j < 4; j++)
        acc[i][j] = __builtin_amdgcn_mfma_f32_16x16x32_bf16(af[i], bf[j], acc[i][j], 0, 0, 0);
    __syncthreads();
  }

  const int cl = lane & 15, rq = (lane >> 4) * 4;
  #pragma unroll
  for (int i = 0; i < 4; i++)
    #pragma unroll
    for (int j = 0; j < 4; j++) {
      int col = n0 + wn + j * 16 + cl;
      #pragma unroll
      for (int r = 0; r < 4; r++) {
        int row = m0 + wm + i * 16 + rq + r;
        float v = acc[i][j][r];
        if (epi == 0) {
          if (col < 512) OutU[(long)row * 512 + col] = f2b(v);
          else           OutZ[(long)row * 512 + (col - 512)] = f2b(v);
        } else {
          long idx = (long)row * N + col;
          OutF[idx] = Xres[idx] + (mask[row] ? v : 0.f);
        }
      }
    }
}

// ---------------- 128x48 bf16 MFMA GEMM for x_proj (K=512), fp32 out -------
__global__ __launch_bounds__(256) void gemm_n48(
    const unsigned short* __restrict__ A, const unsigned short* __restrict__ B,
    float* __restrict__ Out, int K) {
  __shared__ unsigned short As[128 * 32];
  __shared__ unsigned short Bs[48 * 32];
  const int tid = threadIdx.x;
  const int wave = tid >> 6, lane = tid & 63;
  const int m0 = blockIdx.x * 128;
  const int wm = wave * 32;

  f32x4 acc[2][3];
  #pragma unroll
  for (int i = 0; i < 2; i++)
    #pragma unroll
    for (int j = 0; j < 3; j++)
      #pragma unroll
      for (int r = 0; r < 4; r++) acc[i][j][r] = 0.f;

  const int srow = wave * 32 + (lane >> 2);
  const int skcol = (lane & 3) * 8;
  unsigned short* AsW = &As[srow * 32 + skcol];
  const unsigned short* Ag = A + (long)(m0 + srow) * K + skcol;
  const int brow = wave * 16 + (lane >> 2);   // waves 0..2 stage rows 0..47
  unsigned short* BsW = &Bs[brow * 32 + skcol];
  const unsigned short* Bg = B + (long)brow * K + skcol;

  const int fr = lane & 15, fk = (lane >> 4) * 8;

  for (int k0 = 0; k0 < K; k0 += 32) {
    gl2lds16(AsW,           Ag + k0);
    gl2lds16(AsW + 16 * 32, Ag + (long)16 * K + k0);
    if (wave < 3) gl2lds16(BsW, Bg + k0);
    __syncthreads();
    short8 af[2], bf[3];
    #pragma unroll
    for (int i = 0; i < 2; i++)
      af[i] = *(const short8*)&As[(wm + i * 16 + fr) * 32 + fk];
    #pragma unroll
    for (int j = 0; j < 3; j++)
      bf[j] = *(const short8*)&Bs[(j * 16 + fr) * 32 + fk];
    #pragma unroll
    for (int i = 0; i < 2; i++)
      #pragma unroll
      for (int j = 0; j < 3; j++)
        acc[i][j] = __builtin_amdgcn_mfma_f32_16x16x32_bf16(af[i], bf[j], acc[i][j], 0, 0, 0);
    __syncthreads();
  }

  const int cl = lane & 15, rq = (lane >> 4) * 4;
  #pragma unroll
  for (int i = 0; i < 2; i++)
    #pragma unroll
    for (int j = 0; j < 3; j++) {
      int col = j * 16 + cl;
      #pragma unroll
      for (int r = 0; r < 4; r++) {
        int row = m0 + wm + i * 16 + rq + r;
        Out[(long)row * 48 + col] = acc[i][j][r];
      }
    }
}

// ---------------- causal depthwise conv(4) + silu: Upre -> U (bf16) --------
__global__ __launch_bounds__(256) void conv_silu(
    const unsigned short* __restrict__ Upre, const float* __restrict__ cw,
    const float* __restrict__ cb, unsigned short* __restrict__ U) {
  int gid = blockIdx.x * 256 + threadIdx.x;  // local (b,t,d) d fastest (512)
  int d = gid & 511;
  int row = gid >> 9;          // b*2048 + t (chunk-local)
  int t = row & 2047;
  float acc = cb[d];
  #pragma unroll
  for (int k = 0; k < 4; k++) {
    int tt = t + k - 3;
    if (tt >= 0)
      acc = fmaf(b2f(Upre[(long)(row + k - 3) * 512 + d]), cw[d * 4 + k], acc);
  }
  float sg = 1.f / (1.f + __expf(-acc));
  U[gid] = f2b(acc * sg);
}

// ---------------- scan pass 1: per-chunk end state + sum(dt) ---------------
// thread = (b, c, d); chunk length 32, 64 chunks, b chunk-local
__global__ __launch_bounds__(256) void scan_p1(
    const unsigned short* __restrict__ U, const float* __restrict__ XD,
    const float* __restrict__ AA, const float* __restrict__ dtw,
    const float* __restrict__ dtb, float* __restrict__ HCH,
    float* __restrict__ DTS) {
  int gid = blockIdx.x * 256 + threadIdx.x;
  int d = gid & 511;
  int bc = gid >> 9;
  int c = bc & 63, b = bc >> 6;
  const f32x4* aap = (const f32x4*)(AA + d * 16);
  const f32x4* wdp = (const f32x4*)(dtw + d * 16);
  f32x4 aa0 = aap[0], aa1 = aap[1], aa2 = aap[2], aa3 = aap[3];
  f32x4 w0 = wdp[0], w1 = wdp[1], w2 = wdp[2], w3 = wdp[3];
  f32x4 h0 = {0.f,0.f,0.f,0.f}, h1 = h0, h2 = h0, h3 = h0;
  float bias = dtb[d];
  float dts = 0.f;
  int row = b * 2048 + c * 32;
  const unsigned short* Up = U + (long)row * 512 + d;
  for (int tt = 0; tt < 32; tt++, row++, Up += 512) {
    // keep loop-invariant vectors pinned in VGPRs (compiler was reloading them)
    asm volatile("" : "+v"(aa0), "+v"(aa1), "+v"(aa2), "+v"(aa3),
                      "+v"(w0), "+v"(w1), "+v"(w2), "+v"(w3));
    // XD row is wave-uniform: force scalar loads
    int off = __builtin_amdgcn_readfirstlane(row * 48);
    const f32x4* xs = (const f32x4*)(XD + off);
    f32x4 x0 = xs[0], x1 = xs[1], x2 = xs[2], x3 = xs[3];   // dt_in
    f32x4 B0 = xs[4], B1 = xs[5], B2 = xs[6], B3 = xs[7];   // B
    f32x4 pp = x0 * w0 + x1 * w1 + x2 * w2 + x3 * w3;
    float s = bias + pp.x + pp.y + pp.z + pp.w;
    float e = __expf(-fabsf(s));
    float dt = fmaxf(s, 0.f) + __logf(1.f + e);   // softplus
    float du = dt * b2f(*Up);
    h0 = exp2v(dt * aa0) * h0 + du * B0;
    h1 = exp2v(dt * aa1) * h1 + du * B1;
    h2 = exp2v(dt * aa2) * h2 + du * B2;
    h3 = exp2v(dt * aa3) * h3 + du * B3;
    dts += dt;
  }
  f32x4* hp = (f32x4*)(HCH + (long)gid * 16);
  hp[0] = h0; hp[1] = h1; hp[2] = h2; hp[3] = h3;
  DTS[gid] = dts;
}

// ---------------- scan pass 2: prefix over chunks (h_end -> h_start) -------
// thread = (b, d, n), b chunk-local
__global__ __launch_bounds__(256) void scan_p2(
    float* __restrict__ HCH, const float* __restrict__ DTS,
    const float* __restrict__ AA) {
  int gid = blockIdx.x * 256 + threadIdx.x;   // b*8192 + d*16 + n
  int n = gid & 15;
  int d = (gid >> 4) & 511;
  int b = gid >> 13;
  float aa = AA[d * 16 + n];
  float hrun = 0.f;
  for (int c = 0; c < 64; c++) {
    long base = ((long)b * 64 + c) * 512 + d;
    long idx = base * 16 + n;
    float hend = HCH[idx];
    float P = exp2f(DTS[base] * aa);
    HCH[idx] = hrun;            // becomes h_start for chunk c
    hrun = fmaf(P, hrun, hend);
  }
}

// ---------------- scan pass 3: replay with h_start, fused gate -------------
// Y may alias U (same-thread same-element read-before-write)
__global__ __launch_bounds__(256) void scan_p3(
    const unsigned short* __restrict__ U, const unsigned short* __restrict__ Z,
    const float* __restrict__ XD, const float* __restrict__ AA,
    const float* __restrict__ dtw, const float* __restrict__ dtb,
    const float* __restrict__ HCH, const float* __restrict__ skD,
    unsigned short* __restrict__ Y) {
  int gid = blockIdx.x * 256 + threadIdx.x;
  int d = gid & 511;
  int bc = gid >> 9;
  int c = bc & 63, b = bc >> 6;
  const f32x4* aap = (const f32x4*)(AA + d * 16);
  const f32x4* wdp = (const f32x4*)(dtw + d * 16);
  f32x4 aa0 = aap[0], aa1 = aap[1], aa2 = aap[2], aa3 = aap[3];
  f32x4 w0 = wdp[0], w1 = wdp[1], w2 = wdp[2], w3 = wdp[3];
  const f32x4* hp = (const f32x4*)(HCH + (long)gid * 16);
  f32x4 h0 = hp[0], h1 = hp[1], h2 = hp[2], h3 = hp[3];
  float bias = dtb[d];
  float sD = skD[d];
  int row = b * 2048 + c * 32;
  const unsigned short* Up = U + (long)row * 512 + d;
  const unsigned short* Zp = Z + (long)row * 512 + d;
  unsigned short* Yp = Y + (long)row * 512 + d;
  for (int tt = 0; tt < 32; tt++, row++, Up += 512, Zp += 512, Yp += 512) {
    asm volatile("" : "+v"(aa0), "+v"(aa1), "+v"(aa2), "+v"(aa3),
                      "+v"(w0), "+v"(w1), "+v"(w2), "+v"(w3));
    int off = __builtin_amdgcn_readfirstlane(row * 48);
    const f32x4* xs = (const f32x4*)(XD + off);
    f32x4 x0 = xs[0], x1 = xs[1], x2 = xs[2], x3 = xs[3];   // dt_in
    f32x4 B0 = xs[4], B1 = xs[5], B2 = xs[6], B3 = xs[7];   // B
    f32x4 C0 = xs[8], C1 = xs[9], C2 = xs[10], C3 = xs[11]; // C
    f32x4 pp = x0 * w0 + x1 * w1 + x2 * w2 + x3 * w3;
    float s = bias + pp.x + pp.y + pp.z + pp.w;
    float e = __expf(-fabsf(s));
    float dt = fmaxf(s, 0.f) + __logf(1.f + e);
    float u = b2f(*Up);
    float du = dt * u;
    h0 = exp2v(dt * aa0) * h0 + du * B0;
    h1 = exp2v(dt * aa1) * h1 + du * B1;
    h2 = exp2v(dt * aa2) * h2 + du * B2;
    h3 = exp2v(dt * aa3) * h3 + du * B3;
    f32x4 yv = h0 * C0 + h1 * C1 + h2 * C2 + h3 * C3;
    float y = yv.x + yv.y + yv.z + yv.w + u * sD;
    float z = b2f(*Zp);
    float sg = z / (1.f + __expf(-z));      // silu(z)
    *Yp = f2b(y * sg);
  }
}

extern "C" void kernel_launch(void* const* d_in, const int* in_sizes, int n_in,
                              void* d_out, int out_size, void* d_ws, size_t ws_size,
                              hipStream_t stream) {
  const float* x        = (const float*)d_in[0];
  const int*   mask     = (const int*)d_in[1];
  const float* ln_w     = (const float*)d_in[2];
  const float* ln_b     = (const float*)d_in[3];
  const float* in_proj  = (const float*)d_in[4];
  const float* conv_w   = (const float*)d_in[5];
  const float* conv_b   = (const float*)d_in[6];
  const float* x_proj   = (const float*)d_in[7];
  const float* dt_w     = (const float*)d_in[8];
  const float* dt_b     = (const float*)d_in[9];
  const float* A_log    = (const float*)d_in[10];
  const float* skip_D   = (const float*)d_in[11];
  const float* out_proj = (const float*)d_in[12];
  float* X = (float*)d_out;

  // ---- workspace layout (~114 MB total) ----
  char* p = (char*)d_ws;
  auto alloc = [&](size_t n) { char* r = p; p += (n + 255) & ~(size_t)255; return r; };
  unsigned short* WBin  = (unsigned short*)alloc((size_t)2 * 1024 * 256 * 2);  // 1 MB
  unsigned short* WBx   = (unsigned short*)alloc((size_t)2 * 48 * 512 * 2);
  unsigned short* WBout = (unsigned short*)alloc((size_t)2 * 256 * 512 * 2);
  float*          AA    = (float*)alloc((size_t)2 * 512 * 16 * 4);
  char* R_XN   = alloc((size_t)RC * 256 * 2);        // 16 MB: XN, then XD+DTS
  char* R_UPRE = alloc((size_t)RC * 512 * 2);        // 32 MB: Upre, then HCH
  char* R_Z    = alloc((size_t)RC * 512 * 2);        // 32 MB: Z
  char* R_U    = alloc((size_t)RC * 512 * 2);        // 32 MB: U (=Y in-place)

  unsigned short* XN   = (unsigned short*)R_XN;
  float*          XD   = (float*)R_XN;                         // after in_proj
  float*          DTS  = (float*)(R_XN + 8388608);             // 2 MB @ +8 MB
  unsigned short* Upre = (unsigned short*)R_UPRE;
  float*          HCH  = (float*)R_UPRE;                       // after conv
  unsigned short* Z    = (unsigned short*)R_Z;
  unsigned short* U    = (unsigned short*)R_U;

  prep_weights<<<3328, 256, 0, stream>>>(in_proj, x_proj, out_proj, A_log,
                                         WBin, WBx, WBout, AA);
  mask_x<<<65536, 256, 0, stream>>>(x, mask, X);

  for (int ch = 0; ch < 2; ch++) {
    const long row0 = (long)ch * RC;
    float* Xc = X + row0 * 256;
    const int* maskc = mask + row0;
    for (int i = 0; i < 2; i++) {
      ln_fwd<<<RC / 4, 256, 0, stream>>>(Xc, ln_w + i * 256, ln_b + i * 256, XN);
      gemm128<<<dim3(RC / 128, 8), 256, 0, stream>>>(XN, WBin + i * 262144,
          nullptr, Upre, Z, nullptr, nullptr, 1024, 256, 0);
      conv_silu<<<RC * 2, 256, 0, stream>>>(Upre, conv_w + i * 2048,
          conv_b + i * 512, U);
      gemm_n48<<<RC / 128, 256, 0, stream>>>(U, WBx + i * 24576, XD, 512);
      scan_p1<<<BCH * 128, 256, 0, stream>>>(U, XD, AA + i * 8192,
          dt_w + i * 8192, dt_b + i * 512, HCH, DTS);
      scan_p2<<<BCH * 32, 256, 0, stream>>>(HCH, DTS, AA + i * 8192);
      scan_p3<<<BCH * 128, 256, 0, stream>>>(U, Z, XD, AA + i * 8192,
          dt_w + i * 8192, dt_b + i * 512, HCH, skip_D + i * 512, U);
      gemm128<<<dim3(RC / 128, 2), 256, 0, stream>>>(U, WBout + i * 131072,
          Xc, nullptr, nullptr, Xc, maskc, 256, 512, 1);
    }
  }
}

// Round 5
// 1389.344 us; speedup vs baseline: 1.2923x; 1.2005x over previous
//
#include <hip/hip_runtime.h>
#include <cstdint>

#define LOG2E 1.4426950408889634f
#define BCH 16                 // batches per chunk
#define RC  (BCH * 2048)       // rows per chunk = 32768

typedef __attribute__((ext_vector_type(8))) short short8;
typedef __attribute__((ext_vector_type(4))) float f32x4;
typedef __attribute__((ext_vector_type(4))) unsigned short ush4;

__device__ __forceinline__ float b2f(unsigned short u) {
  union { unsigned int u; float f; } c; c.u = ((unsigned int)u) << 16; return c.f;
}
__device__ __forceinline__ unsigned short f2b(float f) {
  union { float f; unsigned int u; } c; c.f = f;
  unsigned int r = c.u + 0x7FFFu + ((c.u >> 16) & 1u);
  return (unsigned short)(r >> 16);
}
// HW exp2: single v_exp_f32, no libcall (exp2f goes through OCML!)
__device__ __forceinline__ float ex2(float x) { return __builtin_amdgcn_exp2f(x); }
__device__ __forceinline__ f32x4 exp2v(f32x4 v) {
  f32x4 r; r.x = ex2(v.x); r.y = ex2(v.y); r.z = ex2(v.z); r.w = ex2(v.w);
  return r;
}

// async global->LDS, 16B/lane; LDS dest contiguous in lane order (base+lane*16B)
__device__ __forceinline__ void gl2lds16(void* l, const void* g) {
  __builtin_amdgcn_global_load_lds(
      (const __attribute__((address_space(1))) void*)g,
      (__attribute__((address_space(3))) void*)l, 16, 0, 0);
}

// ---------------- weight prep: fp32 -> bf16, and AA = -exp(A_log)*log2e ----
__global__ __launch_bounds__(256) void prep_weights(
    const float* __restrict__ inw, const float* __restrict__ xw,
    const float* __restrict__ ow, const float* __restrict__ alog,
    unsigned short* __restrict__ inwb, unsigned short* __restrict__ xwb,
    unsigned short* __restrict__ owb, float* __restrict__ AA) {
  int gid = blockIdx.x * 256 + threadIdx.x;
  const int n_in = 2 * 1024 * 256;   // 524288
  const int n_x  = 2 * 48 * 512;     // 49152
  const int n_o  = 2 * 256 * 512;    // 262144
  const int n_a  = 2 * 512 * 16;     // 16384
  if (gid < n_in) { inwb[gid] = f2b(inw[gid]); return; }
  gid -= n_in;
  if (gid < n_x) { xwb[gid] = f2b(xw[gid]); return; }
  gid -= n_x;
  if (gid < n_o) { owb[gid] = f2b(ow[gid]); return; }
  gid -= n_o;
  if (gid < n_a) { AA[gid] = -__expf(alog[gid]) * LOG2E; }
}

// ---------------- x = x * mask ---------------------------------------------
__global__ __launch_bounds__(256) void mask_x(
    const float* __restrict__ x, const int* __restrict__ mask,
    float* __restrict__ X) {
  int gid = blockIdx.x * 256 + threadIdx.x;     // (b,t,d), d fastest (256)
  int row = gid >> 8;
  X[gid] = mask[row] ? x[gid] : 0.f;
}

// ---------------- LayerNorm: one wave per row, X fp32 -> XN bf16 -----------
__global__ __launch_bounds__(256) void ln_fwd(
    const float* __restrict__ X, const float* __restrict__ w,
    const float* __restrict__ b, unsigned short* __restrict__ XN) {
  int wv = threadIdx.x >> 6, ln = threadIdx.x & 63;
  long row = (long)blockIdx.x * 4 + wv;
  f32x4 v = ((const f32x4*)(X + row * 256))[ln];
  float s = v.x + v.y + v.z + v.w;
  float s2 = v.x * v.x + v.y * v.y + v.z * v.z + v.w * v.w;
  #pragma unroll
  for (int o = 32; o > 0; o >>= 1) {
    s += __shfl_xor(s, o, 64);
    s2 += __shfl_xor(s2, o, 64);
  }
  float mu = s * (1.f / 256.f);
  float var = s2 * (1.f / 256.f) - mu * mu;
  float rst = rsqrtf(var + 1e-5f);
  f32x4 wv4 = ((const f32x4*)w)[ln];
  f32x4 bv4 = ((const f32x4*)b)[ln];
  ush4 o4;
  o4.x = f2b((v.x - mu) * rst * wv4.x + bv4.x);
  o4.y = f2b((v.y - mu) * rst * wv4.y + bv4.y);
  o4.z = f2b((v.z - mu) * rst * wv4.z + bv4.z);
  o4.w = f2b((v.w - mu) * rst * wv4.w + bv4.w);
  ((ush4*)(XN + row * 256))[ln] = o4;
}

// ---------------- 128x128 bf16 MFMA GEMM, C = A(MxK) * B(NxK)^T ------------
// epi==0: split store bf16: col<512 -> OutU, else OutZ
// epi==1: OutF[row*N+col] = Xres[row*N+col] + (mask[row] ? acc : 0)
__global__ __launch_bounds__(256) void gemm128(
    const unsigned short* __restrict__ A, const unsigned short* __restrict__ B,
    const float* __restrict__ Xres, unsigned short* __restrict__ OutU,
    unsigned short* __restrict__ OutZ, float* __restrict__ OutF,
    const int* __restrict__ mask, int N, int K, int epi) {
  __shared__ unsigned short As[128 * 32];
  __shared__ unsigned short Bs[128 * 32];
  const int tid = threadIdx.x;
  const int wave = tid >> 6, lane = tid & 63;
  const int m0 = blockIdx.x * 128, n0 = blockIdx.y * 128;
  const int wm = (wave >> 1) * 64, wn = (wave & 1) * 64;

  f32x4 acc[4][4];
  #pragma unroll
  for (int i = 0; i < 4; i++)
    #pragma unroll
    for (int j = 0; j < 4; j++)
      #pragma unroll
      for (int r = 0; r < 4; r++) acc[i][j][r] = 0.f;

  const int srow = wave * 32 + (lane >> 2);
  const int skcol = (lane & 3) * 8;
  unsigned short* AsW = &As[srow * 32 + skcol];
  unsigned short* BsW = &Bs[srow * 32 + skcol];
  const unsigned short* Ag = A + (long)(m0 + srow) * K + skcol;
  const unsigned short* Bg = B + (long)(n0 + srow) * K + skcol;

  const int fr = lane & 15, fk = (lane >> 4) * 8;

  for (int k0 = 0; k0 < K; k0 += 32) {
    gl2lds16(AsW,            Ag + k0);
    gl2lds16(AsW + 16 * 32,  Ag + (long)16 * K + k0);
    gl2lds16(BsW,            Bg + k0);
    gl2lds16(BsW + 16 * 32,  Bg + (long)16 * K + k0);
    __syncthreads();
    short8 af[4], bf[4];
    #pragma unroll
    for (int i = 0; i < 4; i++) {
      af[i] = *(const short8*)&As[(wm + i * 16 + fr) * 32 + fk];
      bf[i] = *(const short8*)&Bs[(wn + i * 16 + fr) * 32 + fk];
    }
    #pragma unroll
    for (int i = 0; i < 4; i++)
      #pragma unroll
      for (int j = 0; j < 4; j++)
        acc[i][j] = __builtin_amdgcn_mfma_f32_16x16x32_bf16(af[i], bf[j], acc[i][j], 0, 0, 0);
    __syncthreads();
  }

  const int cl = lane & 15, rq = (lane >> 4) * 4;
  #pragma unroll
  for (int i = 0; i < 4; i++)
    #pragma unroll
    for (int j = 0; j < 4; j++) {
      int col = n0 + wn + j * 16 + cl;
      #pragma unroll
      for (int r = 0; r < 4; r++) {
        int row = m0 + wm + i * 16 + rq + r;
        float v = acc[i][j][r];
        if (epi == 0) {
          if (col < 512) OutU[(long)row * 512 + col] = f2b(v);
          else           OutZ[(long)row * 512 + (col - 512)] = f2b(v);
        } else {
          long idx = (long)row * N + col;
          OutF[idx] = Xres[idx] + (mask[row] ? v : 0.f);
        }
      }
    }
}

// ---------------- 128x48 bf16 MFMA GEMM for x_proj (K=512), fp32 out -------
__global__ __launch_bounds__(256) void gemm_n48(
    const unsigned short* __restrict__ A, const unsigned short* __restrict__ B,
    float* __restrict__ Out, int K) {
  __shared__ unsigned short As[128 * 32];
  __shared__ unsigned short Bs[48 * 32];
  const int tid = threadIdx.x;
  const int wave = tid >> 6, lane = tid & 63;
  const int m0 = blockIdx.x * 128;
  const int wm = wave * 32;

  f32x4 acc[2][3];
  #pragma unroll
  for (int i = 0; i < 2; i++)
    #pragma unroll
    for (int j = 0; j < 3; j++)
      #pragma unroll
      for (int r = 0; r < 4; r++) acc[i][j][r] = 0.f;

  const int srow = wave * 32 + (lane >> 2);
  const int skcol = (lane & 3) * 8;
  unsigned short* AsW = &As[srow * 32 + skcol];
  const unsigned short* Ag = A + (long)(m0 + srow) * K + skcol;
  const int brow = wave * 16 + (lane >> 2);   // waves 0..2 stage rows 0..47
  unsigned short* BsW = &Bs[brow * 32 + skcol];
  const unsigned short* Bg = B + (long)brow * K + skcol;

  const int fr = lane & 15, fk = (lane >> 4) * 8;

  for (int k0 = 0; k0 < K; k0 += 32) {
    gl2lds16(AsW,           Ag + k0);
    gl2lds16(AsW + 16 * 32, Ag + (long)16 * K + k0);
    if (wave < 3) gl2lds16(BsW, Bg + k0);
    __syncthreads();
    short8 af[2], bf[3];
    #pragma unroll
    for (int i = 0; i < 2; i++)
      af[i] = *(const short8*)&As[(wm + i * 16 + fr) * 32 + fk];
    #pragma unroll
    for (int j = 0; j < 3; j++)
      bf[j] = *(const short8*)&Bs[(j * 16 + fr) * 32 + fk];
    #pragma unroll
    for (int i = 0; i < 2; i++)
      #pragma unroll
      for (int j = 0; j < 3; j++)
        acc[i][j] = __builtin_amdgcn_mfma_f32_16x16x32_bf16(af[i], bf[j], acc[i][j], 0, 0, 0);
    __syncthreads();
  }

  const int cl = lane & 15, rq = (lane >> 4) * 4;
  #pragma unroll
  for (int i = 0; i < 2; i++)
    #pragma unroll
    for (int j = 0; j < 3; j++) {
      int col = j * 16 + cl;
      #pragma unroll
      for (int r = 0; r < 4; r++) {
        int row = m0 + wm + i * 16 + rq + r;
        Out[(long)row * 48 + col] = acc[i][j][r];
      }
    }
}

// ---------------- causal depthwise conv(4) + silu: Upre -> U (bf16) --------
__global__ __launch_bounds__(256) void conv_silu(
    const unsigned short* __restrict__ Upre, const float* __restrict__ cw,
    const float* __restrict__ cb, unsigned short* __restrict__ U) {
  int gid = blockIdx.x * 256 + threadIdx.x;  // local (b,t,d) d fastest (512)
  int d = gid & 511;
  int row = gid >> 9;          // b*2048 + t (chunk-local)
  int t = row & 2047;
  float acc = cb[d];
  #pragma unroll
  for (int k = 0; k < 4; k++) {
    int tt = t + k - 3;
    if (tt >= 0)
      acc = fmaf(b2f(Upre[(long)(row + k - 3) * 512 + d]), cw[d * 4 + k], acc);
  }
  float sg = 1.f / (1.f + __expf(-acc));
  U[gid] = f2b(acc * sg);
}

// ---------------- scan pass 1: per-chunk end state + sum(dt) ---------------
// thread = (b, c, d); chunk length 32, 64 chunks, b chunk-local
__global__ __launch_bounds__(256) void scan_p1(
    const unsigned short* __restrict__ U, const float* __restrict__ XD,
    const float* __restrict__ AA, const float* __restrict__ dtw,
    const float* __restrict__ dtb, float* __restrict__ HCH,
    float* __restrict__ DTS) {
  int gid = blockIdx.x * 256 + threadIdx.x;
  int d = gid & 511;
  int bc = gid >> 9;
  int c = bc & 63, b = bc >> 6;
  const f32x4* aap = (const f32x4*)(AA + d * 16);
  const f32x4* wdp = (const f32x4*)(dtw + d * 16);
  f32x4 aa0 = aap[0], aa1 = aap[1], aa2 = aap[2], aa3 = aap[3];
  f32x4 w0 = wdp[0], w1 = wdp[1], w2 = wdp[2], w3 = wdp[3];
  f32x4 h0 = {0.f,0.f,0.f,0.f}, h1 = h0, h2 = h0, h3 = h0;
  float bias = dtb[d];
  float dts = 0.f;
  int row = b * 2048 + c * 32;
  const unsigned short* Up = U + (long)row * 512 + d;
  for (int tt = 0; tt < 32; tt++, row++, Up += 512) {
    // XD row is wave-uniform: force scalar loads
    int off = __builtin_amdgcn_readfirstlane(row * 48);
    const f32x4* xs = (const f32x4*)(XD + off);
    f32x4 x0 = xs[0], x1 = xs[1], x2 = xs[2], x3 = xs[3];   // dt_in
    f32x4 B0 = xs[4], B1 = xs[5], B2 = xs[6], B3 = xs[7];   // B
    f32x4 pp = x0 * w0 + x1 * w1 + x2 * w2 + x3 * w3;
    float s = bias + pp.x + pp.y + pp.z + pp.w;
    float e = __expf(-fabsf(s));
    float dt = fmaxf(s, 0.f) + __logf(1.f + e);   // softplus
    float du = dt * b2f(*Up);
    h0 = exp2v(dt * aa0) * h0 + du * B0;
    h1 = exp2v(dt * aa1) * h1 + du * B1;
    h2 = exp2v(dt * aa2) * h2 + du * B2;
    h3 = exp2v(dt * aa3) * h3 + du * B3;
    dts += dt;
  }
  f32x4* hp = (f32x4*)(HCH + (long)gid * 16);
  hp[0] = h0; hp[1] = h1; hp[2] = h2; hp[3] = h3;
  DTS[gid] = dts;
}

// ---------------- scan pass 2: prefix over chunks (h_end -> h_start) -------
// thread = (b, d, n), b chunk-local
__global__ __launch_bounds__(256) void scan_p2(
    float* __restrict__ HCH, const float* __restrict__ DTS,
    const float* __restrict__ AA) {
  int gid = blockIdx.x * 256 + threadIdx.x;   // b*8192 + d*16 + n
  int n = gid & 15;
  int d = (gid >> 4) & 511;
  int b = gid >> 13;
  float aa = AA[d * 16 + n];
  float hrun = 0.f;
  for (int c = 0; c < 64; c++) {
    long base = ((long)b * 64 + c) * 512 + d;
    long idx = base * 16 + n;
    float hend = HCH[idx];
    float P = ex2(DTS[base] * aa);
    HCH[idx] = hrun;            // becomes h_start for chunk c
    hrun = fmaf(P, hrun, hend);
  }
}

// ---------------- scan pass 3: replay with h_start, fused gate -------------
// Y may alias U (same-thread same-element read-before-write)
__global__ __launch_bounds__(256) void scan_p3(
    const unsigned short* __restrict__ U, const unsigned short* __restrict__ Z,
    const float* __restrict__ XD, const float* __restrict__ AA,
    const float* __restrict__ dtw, const float* __restrict__ dtb,
    const float* __restrict__ HCH, const float* __restrict__ skD,
    unsigned short* __restrict__ Y) {
  int gid = blockIdx.x * 256 + threadIdx.x;
  int d = gid & 511;
  int bc = gid >> 9;
  int c = bc & 63, b = bc >> 6;
  const f32x4* aap = (const f32x4*)(AA + d * 16);
  const f32x4* wdp = (const f32x4*)(dtw + d * 16);
  f32x4 aa0 = aap[0], aa1 = aap[1], aa2 = aap[2], aa3 = aap[3];
  f32x4 w0 = wdp[0], w1 = wdp[1], w2 = wdp[2], w3 = wdp[3];
  const f32x4* hp = (const f32x4*)(HCH + (long)gid * 16);
  f32x4 h0 = hp[0], h1 = hp[1], h2 = hp[2], h3 = hp[3];
  float bias = dtb[d];
  float sD = skD[d];
  int row = b * 2048 + c * 32;
  const unsigned short* Up = U + (long)row * 512 + d;
  const unsigned short* Zp = Z + (long)row * 512 + d;
  unsigned short* Yp = Y + (long)row * 512 + d;
  for (int tt = 0; tt < 32; tt++, row++, Up += 512, Zp += 512, Yp += 512) {
    int off = __builtin_amdgcn_readfirstlane(row * 48);
    const f32x4* xs = (const f32x4*)(XD + off);
    f32x4 x0 = xs[0], x1 = xs[1], x2 = xs[2], x3 = xs[3];   // dt_in
    f32x4 B0 = xs[4], B1 = xs[5], B2 = xs[6], B3 = xs[7];   // B
    f32x4 C0 = xs[8], C1 = xs[9], C2 = xs[10], C3 = xs[11]; // C
    f32x4 pp = x0 * w0 + x1 * w1 + x2 * w2 + x3 * w3;
    float s = bias + pp.x + pp.y + pp.z + pp.w;
    float e = __expf(-fabsf(s));
    float dt = fmaxf(s, 0.f) + __logf(1.f + e);
    float u = b2f(*Up);
    float du = dt * u;
    h0 = exp2v(dt * aa0) * h0 + du * B0;
    h1 = exp2v(dt * aa1) * h1 + du * B1;
    h2 = exp2v(dt * aa2) * h2 + du * B2;
    h3 = exp2v(dt * aa3) * h3 + du * B3;
    f32x4 yv = h0 * C0 + h1 * C1 + h2 * C2 + h3 * C3;
    float y = yv.x + yv.y + yv.z + yv.w + u * sD;
    float z = b2f(*Zp);
    float sg = z / (1.f + __expf(-z));      // silu(z)
    *Yp = f2b(y * sg);
  }
}

extern "C" void kernel_launch(void* const* d_in, const int* in_sizes, int n_in,
                              void* d_out, int out_size, void* d_ws, size_t ws_size,
                              hipStream_t stream) {
  const float* x        = (const float*)d_in[0];
  const int*   mask     = (const int*)d_in[1];
  const float* ln_w     = (const float*)d_in[2];
  const float* ln_b     = (const float*)d_in[3];
  const float* in_proj  = (const float*)d_in[4];
  const float* conv_w   = (const float*)d_in[5];
  const float* conv_b   = (const float*)d_in[6];
  const float* x_proj   = (const float*)d_in[7];
  const float* dt_w     = (const float*)d_in[8];
  const float* dt_b     = (const float*)d_in[9];
  const float* A_log    = (const float*)d_in[10];
  const float* skip_D   = (const float*)d_in[11];
  const float* out_proj = (const float*)d_in[12];
  float* X = (float*)d_out;

  // ---- workspace layout (~114 MB total) ----
  char* p = (char*)d_ws;
  auto alloc = [&](size_t n) { char* r = p; p += (n + 255) & ~(size_t)255; return r; };
  unsigned short* WBin  = (unsigned short*)alloc((size_t)2 * 1024 * 256 * 2);  // 1 MB
  unsigned short* WBx   = (unsigned short*)alloc((size_t)2 * 48 * 512 * 2);
  unsigned short* WBout = (unsigned short*)alloc((size_t)2 * 256 * 512 * 2);
  float*          AA    = (float*)alloc((size_t)2 * 512 * 16 * 4);
  char* R_XN   = alloc((size_t)RC * 256 * 2);        // 16 MB: XN, then XD+DTS
  char* R_UPRE = alloc((size_t)RC * 512 * 2);        // 32 MB: Upre, then HCH
  char* R_Z    = alloc((size_t)RC * 512 * 2);        // 32 MB: Z
  char* R_U    = alloc((size_t)RC * 512 * 2);        // 32 MB: U (=Y in-place)

  unsigned short* XN   = (unsigned short*)R_XN;
  float*          XD   = (float*)R_XN;                         // after in_proj
  float*          DTS  = (float*)(R_XN + 8388608);             // 2 MB @ +8 MB
  unsigned short* Upre = (unsigned short*)R_UPRE;
  float*          HCH  = (float*)R_UPRE;                       // after conv
  unsigned short* Z    = (unsigned short*)R_Z;
  unsigned short* U    = (unsigned short*)R_U;

  prep_weights<<<3328, 256, 0, stream>>>(in_proj, x_proj, out_proj, A_log,
                                         WBin, WBx, WBout, AA);
  mask_x<<<65536, 256, 0, stream>>>(x, mask, X);

  for (int ch = 0; ch < 2; ch++) {
    const long row0 = (long)ch * RC;
    float* Xc = X + row0 * 256;
    const int* maskc = mask + row0;
    for (int i = 0; i < 2; i++) {
      ln_fwd<<<RC / 4, 256, 0, stream>>>(Xc, ln_w + i * 256, ln_b + i * 256, XN);
      gemm128<<<dim3(RC / 128, 8), 256, 0, stream>>>(XN, WBin + i * 262144,
          nullptr, Upre, Z, nullptr, nullptr, 1024, 256, 0);
      conv_silu<<<RC * 2, 256, 0, stream>>>(Upre, conv_w + i * 2048,
          conv_b + i * 512, U);
      gemm_n48<<<RC / 128, 256, 0, stream>>>(U, WBx + i * 24576, XD, 512);
      scan_p1<<<BCH * 128, 256, 0, stream>>>(U, XD, AA + i * 8192,
          dt_w + i * 8192, dt_b + i * 512, HCH, DTS);
      scan_p2<<<BCH * 32, 256, 0, stream>>>(HCH, DTS, AA + i * 8192);
      scan_p3<<<BCH * 128, 256, 0, stream>>>(U, Z, XD, AA + i * 8192,
          dt_w + i * 8192, dt_b + i * 512, HCH, skip_D + i * 512, U);
      gemm128<<<dim3(RC / 128, 2), 256, 0, stream>>>(U, WBout + i * 131072,
          Xc, nullptr, nullptr, Xc, maskc, 256, 512, 1);
    }
  }
}

// Round 6
// 1239.958 us; speedup vs baseline: 1.4480x; 1.1205x over previous
//
#include <hip/hip_runtime.h>
#include <cstdint>

#define LOG2E 1.4426950408889634f
#define BCH 16                 // batches per chunk
#define RC  (BCH * 2048)       // rows per chunk = 32768

typedef __attribute__((ext_vector_type(8))) short short8;
typedef __attribute__((ext_vector_type(4))) float f32x4;
typedef __attribute__((ext_vector_type(4))) unsigned short ush4;
typedef __attribute__((ext_vector_type(8))) unsigned short ush8;

__device__ __forceinline__ float b2f(unsigned short u) {
  union { unsigned int u; float f; } c; c.u = ((unsigned int)u) << 16; return c.f;
}
__device__ __forceinline__ unsigned short f2b(float f) {
  union { float f; unsigned int u; } c; c.f = f;
  unsigned int r = c.u + 0x7FFFu + ((c.u >> 16) & 1u);
  return (unsigned short)(r >> 16);
}
// HW exp2: single v_exp_f32, no libcall (exp2f goes through OCML!)
__device__ __forceinline__ float ex2(float x) { return __builtin_amdgcn_exp2f(x); }
__device__ __forceinline__ f32x4 exp2v(f32x4 v) {
  f32x4 r; r.x = ex2(v.x); r.y = ex2(v.y); r.z = ex2(v.z); r.w = ex2(v.w);
  return r;
}

// async global->LDS, 16B/lane; LDS dest contiguous in lane order (base+lane*16B)
__device__ __forceinline__ void gl2lds16(void* l, const void* g) {
  __builtin_amdgcn_global_load_lds(
      (const __attribute__((address_space(1))) void*)g,
      (__attribute__((address_space(3))) void*)l, 16, 0, 0);
}

// ---------------- weight prep: fp32 -> bf16, and AA = -exp(A_log)*log2e ----
__global__ __launch_bounds__(256) void prep_weights(
    const float* __restrict__ inw, const float* __restrict__ xw,
    const float* __restrict__ ow, const float* __restrict__ alog,
    unsigned short* __restrict__ inwb, unsigned short* __restrict__ xwb,
    unsigned short* __restrict__ owb, float* __restrict__ AA) {
  int gid = blockIdx.x * 256 + threadIdx.x;
  const int n_in = 2 * 1024 * 256;   // 524288
  const int n_x  = 2 * 48 * 512;     // 49152
  const int n_o  = 2 * 256 * 512;    // 262144
  const int n_a  = 2 * 512 * 16;     // 16384
  if (gid < n_in) { inwb[gid] = f2b(inw[gid]); return; }
  gid -= n_in;
  if (gid < n_x) { xwb[gid] = f2b(xw[gid]); return; }
  gid -= n_x;
  if (gid < n_o) { owb[gid] = f2b(ow[gid]); return; }
  gid -= n_o;
  if (gid < n_a) { AA[gid] = -__expf(alog[gid]) * LOG2E; }
}

// ---------------- x = x * mask ---------------------------------------------
__global__ __launch_bounds__(256) void mask_x(
    const float* __restrict__ x, const int* __restrict__ mask,
    float* __restrict__ X) {
  int gid = blockIdx.x * 256 + threadIdx.x;     // (b,t,d), d fastest (256)
  int row = gid >> 8;
  X[gid] = mask[row] ? x[gid] : 0.f;
}

// ---------------- LayerNorm: one wave per row, X fp32 -> XN bf16 -----------
__global__ __launch_bounds__(256) void ln_fwd(
    const float* __restrict__ X, const float* __restrict__ w,
    const float* __restrict__ b, unsigned short* __restrict__ XN) {
  int wv = threadIdx.x >> 6, ln = threadIdx.x & 63;
  long row = (long)blockIdx.x * 4 + wv;
  f32x4 v = ((const f32x4*)(X + row * 256))[ln];
  float s = v.x + v.y + v.z + v.w;
  float s2 = v.x * v.x + v.y * v.y + v.z * v.z + v.w * v.w;
  #pragma unroll
  for (int o = 32; o > 0; o >>= 1) {
    s += __shfl_xor(s, o, 64);
    s2 += __shfl_xor(s2, o, 64);
  }
  float mu = s * (1.f / 256.f);
  float var = s2 * (1.f / 256.f) - mu * mu;
  float rst = rsqrtf(var + 1e-5f);
  f32x4 wv4 = ((const f32x4*)w)[ln];
  f32x4 bv4 = ((const f32x4*)b)[ln];
  ush4 o4;
  o4.x = f2b((v.x - mu) * rst * wv4.x + bv4.x);
  o4.y = f2b((v.y - mu) * rst * wv4.y + bv4.y);
  o4.z = f2b((v.z - mu) * rst * wv4.z + bv4.z);
  o4.w = f2b((v.w - mu) * rst * wv4.w + bv4.w);
  ((ush4*)(XN + row * 256))[ln] = o4;
}

// ---------------- 128x128 bf16 MFMA GEMM, C = A(MxK) * B(NxK)^T ------------
// epi==0: split store bf16: col<512 -> OutU, else OutZ
// epi==1: OutF[row*N+col] = Xres[row*N+col] + (mask[row] ? acc : 0)
__global__ __launch_bounds__(256) void gemm128(
    const unsigned short* __restrict__ A, const unsigned short* __restrict__ B,
    const float* __restrict__ Xres, unsigned short* __restrict__ OutU,
    unsigned short* __restrict__ OutZ, float* __restrict__ OutF,
    const int* __restrict__ mask, int N, int K, int epi) {
  __shared__ unsigned short As[128 * 32];
  __shared__ unsigned short Bs[128 * 32];
  const int tid = threadIdx.x;
  const int wave = tid >> 6, lane = tid & 63;
  const int m0 = blockIdx.x * 128, n0 = blockIdx.y * 128;
  const int wm = (wave >> 1) * 64, wn = (wave & 1) * 64;

  f32x4 acc[4][4];
  #pragma unroll
  for (int i = 0; i < 4; i++)
    #pragma unroll
    for (int j = 0; j < 4; j++)
      #pragma unroll
      for (int r = 0; r < 4; r++) acc[i][j][r] = 0.f;

  const int srow = wave * 32 + (lane >> 2);
  const int skcol = (lane & 3) * 8;
  unsigned short* AsW = &As[srow * 32 + skcol];
  unsigned short* BsW = &Bs[srow * 32 + skcol];
  const unsigned short* Ag = A + (long)(m0 + srow) * K + skcol;
  const unsigned short* Bg = B + (long)(n0 + srow) * K + skcol;

  const int fr = lane & 15, fk = (lane >> 4) * 8;

  for (int k0 = 0; k0 < K; k0 += 32) {
    gl2lds16(AsW,            Ag + k0);
    gl2lds16(AsW + 16 * 32,  Ag + (long)16 * K + k0);
    gl2lds16(BsW,            Bg + k0);
    gl2lds16(BsW + 16 * 32,  Bg + (long)16 * K + k0);
    __syncthreads();
    short8 af[4], bf[4];
    #pragma unroll
    for (int i = 0; i < 4; i++) {
      af[i] = *(const short8*)&As[(wm + i * 16 + fr) * 32 + fk];
      bf[i] = *(const short8*)&Bs[(wn + i * 16 + fr) * 32 + fk];
    }
    #pragma unroll
    for (int i = 0; i < 4; i++)
      #pragma unroll
      for (int j = 0; j < 4; j++)
        acc[i][j] = __builtin_amdgcn_mfma_f32_16x16x32_bf16(af[i], bf[j], acc[i][j], 0, 0, 0);
    __syncthreads();
  }

  const int cl = lane & 15, rq = (lane >> 4) * 4;
  #pragma unroll
  for (int i = 0; i < 4; i++)
    #pragma unroll
    for (int j = 0; j < 4; j++) {
      int col = n0 + wn + j * 16 + cl;
      #pragma unroll
      for (int r = 0; r < 4; r++) {
        int row = m0 + wm + i * 16 + rq + r;
        float v = acc[i][j][r];
        if (epi == 0) {
          if (col < 512) OutU[(long)row * 512 + col] = f2b(v);
          else           OutZ[(long)row * 512 + (col - 512)] = f2b(v);
        } else {
          long idx = (long)row * N + col;
          OutF[idx] = Xres[idx] + (mask[row] ? v : 0.f);
        }
      }
    }
}

// ---------------- 128x48 bf16 MFMA GEMM for x_proj (K=512), fp32 out -------
__global__ __launch_bounds__(256) void gemm_n48(
    const unsigned short* __restrict__ A, const unsigned short* __restrict__ B,
    float* __restrict__ Out, int K) {
  __shared__ unsigned short As[128 * 32];
  __shared__ unsigned short Bs[48 * 32];
  const int tid = threadIdx.x;
  const int wave = tid >> 6, lane = tid & 63;
  const int m0 = blockIdx.x * 128;
  const int wm = wave * 32;

  f32x4 acc[2][3];
  #pragma unroll
  for (int i = 0; i < 2; i++)
    #pragma unroll
    for (int j = 0; j < 3; j++)
      #pragma unroll
      for (int r = 0; r < 4; r++) acc[i][j][r] = 0.f;

  const int srow = wave * 32 + (lane >> 2);
  const int skcol = (lane & 3) * 8;
  unsigned short* AsW = &As[srow * 32 + skcol];
  const unsigned short* Ag = A + (long)(m0 + srow) * K + skcol;
  const int brow = wave * 16 + (lane >> 2);   // waves 0..2 stage rows 0..47
  unsigned short* BsW = &Bs[brow * 32 + skcol];
  const unsigned short* Bg = B + (long)brow * K + skcol;

  const int fr = lane & 15, fk = (lane >> 4) * 8;

  for (int k0 = 0; k0 < K; k0 += 32) {
    gl2lds16(AsW,           Ag + k0);
    gl2lds16(AsW + 16 * 32, Ag + (long)16 * K + k0);
    if (wave < 3) gl2lds16(BsW, Bg + k0);
    __syncthreads();
    short8 af[2], bf[3];
    #pragma unroll
    for (int i = 0; i < 2; i++)
      af[i] = *(const short8*)&As[(wm + i * 16 + fr) * 32 + fk];
    #pragma unroll
    for (int j = 0; j < 3; j++)
      bf[j] = *(const short8*)&Bs[(j * 16 + fr) * 32 + fk];
    #pragma unroll
    for (int i = 0; i < 2; i++)
      #pragma unroll
      for (int j = 0; j < 3; j++)
        acc[i][j] = __builtin_amdgcn_mfma_f32_16x16x32_bf16(af[i], bf[j], acc[i][j], 0, 0, 0);
    __syncthreads();
  }

  const int cl = lane & 15, rq = (lane >> 4) * 4;
  #pragma unroll
  for (int i = 0; i < 2; i++)
    #pragma unroll
    for (int j = 0; j < 3; j++) {
      int col = j * 16 + cl;
      #pragma unroll
      for (int r = 0; r < 4; r++) {
        int row = m0 + wm + i * 16 + rq + r;
        Out[(long)row * 48 + col] = acc[i][j][r];
      }
    }
}

// ---------------- causal depthwise conv(4) + silu, 8 d per thread ----------
// thread: d8 = tid&63 (d = d8*8), row = gid>>6; one wave spans one row
__global__ __launch_bounds__(256, 4) void conv_silu(
    const unsigned short* __restrict__ Upre, const float* __restrict__ cw,
    const float* __restrict__ cb, unsigned short* __restrict__ U) {
  int gid = blockIdx.x * 256 + threadIdx.x;
  int d8 = gid & 63;
  int row = gid >> 6;          // b*2048 + t (chunk-local)
  int t = row & 2047;
  int d0 = d8 * 8;
  // tap weights: cw[d][k], 4 contiguous per d
  f32x4 cwv[8];
  #pragma unroll
  for (int di = 0; di < 8; di++) cwv[di] = ((const f32x4*)(cw + (d0 + di) * 4))[0];
  f32x4 cbv0 = ((const f32x4*)(cb + d0))[0];
  f32x4 cbv1 = ((const f32x4*)(cb + d0))[1];
  float acc[8] = {cbv0.x, cbv0.y, cbv0.z, cbv0.w, cbv1.x, cbv1.y, cbv1.z, cbv1.w};
  #pragma unroll
  for (int k = 0; k < 4; k++) {
    int tt = t + k - 3;
    if (tt >= 0) {          // wave-uniform branch
      ush8 uv = *(const ush8*)(Upre + (long)(row + k - 3) * 512 + d0);
      #pragma unroll
      for (int di = 0; di < 8; di++)
        acc[di] = fmaf(b2f(uv[di]), cwv[di][k], acc[di]);
    }
  }
  ush8 o;
  #pragma unroll
  for (int di = 0; di < 8; di++) {
    float sg = 1.f / (1.f + __expf(-acc[di]));
    o[di] = f2b(acc[di] * sg);
  }
  *(ush8*)(U + (long)row * 512 + d0) = o;
}

// ---------------- scan pass 1: per-chunk end state + sum(dt) ---------------
// thread = (b, c, d); chunk length 32, 64 chunks, b chunk-local
__global__ __launch_bounds__(256, 4) void scan_p1(
    const unsigned short* __restrict__ U, const float* __restrict__ XD,
    const float* __restrict__ AA, const float* __restrict__ dtw,
    const float* __restrict__ dtb, float* __restrict__ HCH,
    float* __restrict__ DTS) {
  int gid = blockIdx.x * 256 + threadIdx.x;
  int d = gid & 511;
  int bc = gid >> 9;
  int c = bc & 63, b = bc >> 6;
  const f32x4* aap = (const f32x4*)(AA + d * 16);
  const f32x4* wdp = (const f32x4*)(dtw + d * 16);
  f32x4 aa0 = aap[0], aa1 = aap[1], aa2 = aap[2], aa3 = aap[3];
  f32x4 w0 = wdp[0], w1 = wdp[1], w2 = wdp[2], w3 = wdp[3];
  f32x4 h0 = {0.f,0.f,0.f,0.f}, h1 = h0, h2 = h0, h3 = h0;
  float bias = dtb[d];
  float dts = 0.f;
  int row = b * 2048 + c * 32;
  const unsigned short* Up = U + (long)row * 512 + d;
  for (int tt = 0; tt < 32; tt++, row++, Up += 512) {
    // XD row is wave-uniform: force scalar loads
    int off = __builtin_amdgcn_readfirstlane(row * 48);
    const f32x4* xs = (const f32x4*)(XD + off);
    f32x4 x0 = xs[0], x1 = xs[1], x2 = xs[2], x3 = xs[3];   // dt_in
    f32x4 B0 = xs[4], B1 = xs[5], B2 = xs[6], B3 = xs[7];   // B
    f32x4 pp = x0 * w0 + x1 * w1 + x2 * w2 + x3 * w3;
    float s = bias + pp.x + pp.y + pp.z + pp.w;
    float e = __expf(-fabsf(s));
    float dt = fmaxf(s, 0.f) + __logf(1.f + e);   // softplus
    float du = dt * b2f(*Up);
    h0 = exp2v(dt * aa0) * h0 + du * B0;
    h1 = exp2v(dt * aa1) * h1 + du * B1;
    h2 = exp2v(dt * aa2) * h2 + du * B2;
    h3 = exp2v(dt * aa3) * h3 + du * B3;
    dts += dt;
  }
  f32x4* hp = (f32x4*)(HCH + (long)gid * 16);
  hp[0] = h0; hp[1] = h1; hp[2] = h2; hp[3] = h3;
  DTS[gid] = dts;
}

// ---------------- scan pass 2: prefix over chunks (h_end -> h_start) -------
// thread = (b, d, n), b chunk-local
__global__ __launch_bounds__(256) void scan_p2(
    float* __restrict__ HCH, const float* __restrict__ DTS,
    const float* __restrict__ AA) {
  int gid = blockIdx.x * 256 + threadIdx.x;   // b*8192 + d*16 + n
  int n = gid & 15;
  int d = (gid >> 4) & 511;
  int b = gid >> 13;
  float aa = AA[d * 16 + n];
  float hrun = 0.f;
  for (int c = 0; c < 64; c++) {
    long base = ((long)b * 64 + c) * 512 + d;
    long idx = base * 16 + n;
    float hend = HCH[idx];
    float P = ex2(DTS[base] * aa);
    HCH[idx] = hrun;            // becomes h_start for chunk c
    hrun = fmaf(P, hrun, hend);
  }
}

// ---------------- scan pass 3: replay with h_start, fused gate -------------
// Y may alias U (same-thread same-element read-before-write)
__global__ __launch_bounds__(256, 4) void scan_p3(
    const unsigned short* __restrict__ U, const unsigned short* __restrict__ Z,
    const float* __restrict__ XD, const float* __restrict__ AA,
    const float* __restrict__ dtw, const float* __restrict__ dtb,
    const float* __restrict__ HCH, const float* __restrict__ skD,
    unsigned short* __restrict__ Y) {
  int gid = blockIdx.x * 256 + threadIdx.x;
  int d = gid & 511;
  int bc = gid >> 9;
  int c = bc & 63, b = bc >> 6;
  const f32x4* aap = (const f32x4*)(AA + d * 16);
  const f32x4* wdp = (const f32x4*)(dtw + d * 16);
  f32x4 aa0 = aap[0], aa1 = aap[1], aa2 = aap[2], aa3 = aap[3];
  f32x4 w0 = wdp[0], w1 = wdp[1], w2 = wdp[2], w3 = wdp[3];
  const f32x4* hp = (const f32x4*)(HCH + (long)gid * 16);
  f32x4 h0 = hp[0], h1 = hp[1], h2 = hp[2], h3 = hp[3];
  float bias = dtb[d];
  float sD = skD[d];
  int row = b * 2048 + c * 32;
  const unsigned short* Up = U + (long)row * 512 + d;
  const unsigned short* Zp = Z + (long)row * 512 + d;
  unsigned short* Yp = Y + (long)row * 512 + d;
  for (int tt = 0; tt < 32; tt++, row++, Up += 512, Zp += 512, Yp += 512) {
    int off = __builtin_amdgcn_readfirstlane(row * 48);
    const f32x4* xs = (const f32x4*)(XD + off);
    f32x4 x0 = xs[0], x1 = xs[1], x2 = xs[2], x3 = xs[3];   // dt_in
    f32x4 B0 = xs[4], B1 = xs[5], B2 = xs[6], B3 = xs[7];   // B
    f32x4 C0 = xs[8], C1 = xs[9], C2 = xs[10], C3 = xs[11]; // C
    f32x4 pp = x0 * w0 + x1 * w1 + x2 * w2 + x3 * w3;
    float s = bias + pp.x + pp.y + pp.z + pp.w;
    float e = __expf(-fabsf(s));
    float dt = fmaxf(s, 0.f) + __logf(1.f + e);
    float u = b2f(*Up);
    float du = dt * u;
    h0 = exp2v(dt * aa0) * h0 + du * B0;
    h1 = exp2v(dt * aa1) * h1 + du * B1;
    h2 = exp2v(dt * aa2) * h2 + du * B2;
    h3 = exp2v(dt * aa3) * h3 + du * B3;
    f32x4 yv = h0 * C0 + h1 * C1 + h2 * C2 + h3 * C3;
    float y = yv.x + yv.y + yv.z + yv.w + u * sD;
    float z = b2f(*Zp);
    float sg = z / (1.f + __expf(-z));      // silu(z)
    *Yp = f2b(y * sg);
  }
}

extern "C" void kernel_launch(void* const* d_in, const int* in_sizes, int n_in,
                              void* d_out, int out_size, void* d_ws, size_t ws_size,
                              hipStream_t stream) {
  const float* x        = (const float*)d_in[0];
  const int*   mask     = (const int*)d_in[1];
  const float* ln_w     = (const float*)d_in[2];
  const float* ln_b     = (const float*)d_in[3];
  const float* in_proj  = (const float*)d_in[4];
  const float* conv_w   = (const float*)d_in[5];
  const float* conv_b   = (const float*)d_in[6];
  const float* x_proj   = (const float*)d_in[7];
  const float* dt_w     = (const float*)d_in[8];
  const float* dt_b     = (const float*)d_in[9];
  const float* A_log    = (const float*)d_in[10];
  const float* skip_D   = (const float*)d_in[11];
  const float* out_proj = (const float*)d_in[12];
  float* X = (float*)d_out;

  // ---- workspace layout (~114 MB total) ----
  char* p = (char*)d_ws;
  auto alloc = [&](size_t n) { char* r = p; p += (n + 255) & ~(size_t)255; return r; };
  unsigned short* WBin  = (unsigned short*)alloc((size_t)2 * 1024 * 256 * 2);  // 1 MB
  unsigned short* WBx   = (unsigned short*)alloc((size_t)2 * 48 * 512 * 2);
  unsigned short* WBout = (unsigned short*)alloc((size_t)2 * 256 * 512 * 2);
  float*          AA    = (float*)alloc((size_t)2 * 512 * 16 * 4);
  char* R_XN   = alloc((size_t)RC * 256 * 2);        // 16 MB: XN, then XD+DTS
  char* R_UPRE = alloc((size_t)RC * 512 * 2);        // 32 MB: Upre, then HCH
  char* R_Z    = alloc((size_t)RC * 512 * 2);        // 32 MB: Z
  char* R_U    = alloc((size_t)RC * 512 * 2);        // 32 MB: U (=Y in-place)

  unsigned short* XN   = (unsigned short*)R_XN;
  float*          XD   = (float*)R_XN;                         // after in_proj
  float*          DTS  = (float*)(R_XN + 8388608);             // 2 MB @ +8 MB
  unsigned short* Upre = (unsigned short*)R_UPRE;
  float*          HCH  = (float*)R_UPRE;                       // after conv
  unsigned short* Z    = (unsigned short*)R_Z;
  unsigned short* U    = (unsigned short*)R_U;

  prep_weights<<<3328, 256, 0, stream>>>(in_proj, x_proj, out_proj, A_log,
                                         WBin, WBx, WBout, AA);
  mask_x<<<65536, 256, 0, stream>>>(x, mask, X);

  for (int ch = 0; ch < 2; ch++) {
    const long row0 = (long)ch * RC;
    float* Xc = X + row0 * 256;
    const int* maskc = mask + row0;
    for (int i = 0; i < 2; i++) {
      ln_fwd<<<RC / 4, 256, 0, stream>>>(Xc, ln_w + i * 256, ln_b + i * 256, XN);
      gemm128<<<dim3(RC / 128, 8), 256, 0, stream>>>(XN, WBin + i * 262144,
          nullptr, Upre, Z, nullptr, nullptr, 1024, 256, 0);
      conv_silu<<<RC / 4, 256, 0, stream>>>(Upre, conv_w + i * 2048,
          conv_b + i * 512, U);
      gemm_n48<<<RC / 128, 256, 0, stream>>>(U, WBx + i * 24576, XD, 512);
      scan_p1<<<BCH * 128, 256, 0, stream>>>(U, XD, AA + i * 8192,
          dt_w + i * 8192, dt_b + i * 512, HCH, DTS);
      scan_p2<<<BCH * 32, 256, 0, stream>>>(HCH, DTS, AA + i * 8192);
      scan_p3<<<BCH * 128, 256, 0, stream>>>(U, Z, XD, AA + i * 8192,
          dt_w + i * 8192, dt_b + i * 512, HCH, skip_D + i * 512, U);
      gemm128<<<dim3(RC / 128, 2), 256, 0, stream>>>(U, WBout + i * 131072,
          Xc, nullptr, nullptr, Xc, maskc, 256, 512, 1);
    }
  }
}

// Round 8
// 1207.659 us; speedup vs baseline: 1.4867x; 1.0267x over previous
//
#include <hip/hip_runtime.h>
#include <cstdint>

#define LOG2E 1.4426950408889634f
#define BCH 16                 // batches per chunk
#define RC  (BCH * 2048)       // rows per chunk = 32768

typedef __attribute__((ext_vector_type(8))) short short8;
typedef __attribute__((ext_vector_type(4))) float f32x4;
typedef __attribute__((ext_vector_type(4))) unsigned short ush4;
typedef __attribute__((ext_vector_type(8))) unsigned short ush8;

__device__ __forceinline__ float b2f(unsigned short u) {
  union { unsigned int u; float f; } c; c.u = ((unsigned int)u) << 16; return c.f;
}
__device__ __forceinline__ unsigned short f2b(float f) {
  union { float f; unsigned int u; } c; c.f = f;
  unsigned int r = c.u + 0x7FFFu + ((c.u >> 16) & 1u);
  return (unsigned short)(r >> 16);
}
// HW exp2: single v_exp_f32, no libcall (exp2f goes through OCML!)
__device__ __forceinline__ float ex2(float x) { return __builtin_amdgcn_exp2f(x); }
__device__ __forceinline__ f32x4 exp2v(f32x4 v) {
  f32x4 r; r.x = ex2(v.x); r.y = ex2(v.y); r.z = ex2(v.z); r.w = ex2(v.w);
  return r;
}

// opaque 16B load: result cannot be rematerialized -> stays in VGPRs
__device__ __forceinline__ f32x4 ld4(const float* p) {
  f32x4 r;
  asm volatile("global_load_dwordx4 %0, %1, off" : "=v"(r) : "v"(p));
  return r;
}

// async global->LDS, 16B/lane; LDS dest contiguous in lane order (base+lane*16B)
__device__ __forceinline__ void gl2lds16(void* l, const void* g) {
  __builtin_amdgcn_global_load_lds(
      (const __attribute__((address_space(1))) void*)g,
      (__attribute__((address_space(3))) void*)l, 16, 0, 0);
}

// ---------------- weight prep: fp32 -> bf16, and AA = -exp(A_log)*log2e ----
__global__ __launch_bounds__(256) void prep_weights(
    const float* __restrict__ inw, const float* __restrict__ xw,
    const float* __restrict__ ow, const float* __restrict__ alog,
    unsigned short* __restrict__ inwb, unsigned short* __restrict__ xwb,
    unsigned short* __restrict__ owb, float* __restrict__ AA) {
  int gid = blockIdx.x * 256 + threadIdx.x;
  const int n_in = 2 * 1024 * 256;   // 524288
  const int n_x  = 2 * 48 * 512;     // 49152
  const int n_o  = 2 * 256 * 512;    // 262144
  const int n_a  = 2 * 512 * 16;     // 16384
  if (gid < n_in) { inwb[gid] = f2b(inw[gid]); return; }
  gid -= n_in;
  if (gid < n_x) { xwb[gid] = f2b(xw[gid]); return; }
  gid -= n_x;
  if (gid < n_o) { owb[gid] = f2b(ow[gid]); return; }
  gid -= n_o;
  if (gid < n_a) { AA[gid] = -__expf(alog[gid]) * LOG2E; }
}

// ---------------- x = x * mask ---------------------------------------------
__global__ __launch_bounds__(256) void mask_x(
    const float* __restrict__ x, const int* __restrict__ mask,
    float* __restrict__ X) {
  int gid = blockIdx.x * 256 + threadIdx.x;     // (b,t,d), d fastest (256)
  int row = gid >> 8;
  X[gid] = mask[row] ? x[gid] : 0.f;
}

// ---------------- LayerNorm: one wave per row, X fp32 -> XN bf16 -----------
__global__ __launch_bounds__(256) void ln_fwd(
    const float* __restrict__ X, const float* __restrict__ w,
    const float* __restrict__ b, unsigned short* __restrict__ XN) {
  int wv = threadIdx.x >> 6, ln = threadIdx.x & 63;
  long row = (long)blockIdx.x * 4 + wv;
  f32x4 v = ((const f32x4*)(X + row * 256))[ln];
  float s = v.x + v.y + v.z + v.w;
  float s2 = v.x * v.x + v.y * v.y + v.z * v.z + v.w * v.w;
  #pragma unroll
  for (int o = 32; o > 0; o >>= 1) {
    s += __shfl_xor(s, o, 64);
    s2 += __shfl_xor(s2, o, 64);
  }
  float mu = s * (1.f / 256.f);
  float var = s2 * (1.f / 256.f) - mu * mu;
  float rst = rsqrtf(var + 1e-5f);
  f32x4 wv4 = ((const f32x4*)w)[ln];
  f32x4 bv4 = ((const f32x4*)b)[ln];
  ush4 o4;
  o4.x = f2b((v.x - mu) * rst * wv4.x + bv4.x);
  o4.y = f2b((v.y - mu) * rst * wv4.y + bv4.y);
  o4.z = f2b((v.z - mu) * rst * wv4.z + bv4.z);
  o4.w = f2b((v.w - mu) * rst * wv4.w + bv4.w);
  ((ush4*)(XN + row * 256))[ln] = o4;
}

// ---------------- 128x128 bf16 MFMA GEMM, C = A(MxK) * B(NxK)^T ------------
// split store bf16: col<512 -> OutU, else OutZ (for in_proj)
__global__ __launch_bounds__(256) void gemm128(
    const unsigned short* __restrict__ A, const unsigned short* __restrict__ B,
    unsigned short* __restrict__ OutU, unsigned short* __restrict__ OutZ,
    int N, int K) {
  __shared__ unsigned short As[128 * 32];
  __shared__ unsigned short Bs[128 * 32];
  const int tid = threadIdx.x;
  const int wave = tid >> 6, lane = tid & 63;
  const int m0 = blockIdx.x * 128, n0 = blockIdx.y * 128;
  const int wm = (wave >> 1) * 64, wn = (wave & 1) * 64;

  f32x4 acc[4][4];
  #pragma unroll
  for (int i = 0; i < 4; i++)
    #pragma unroll
    for (int j = 0; j < 4; j++)
      #pragma unroll
      for (int r = 0; r < 4; r++) acc[i][j][r] = 0.f;

  const int srow = wave * 32 + (lane >> 2);
  const int skcol = (lane & 3) * 8;
  unsigned short* AsW = &As[srow * 32 + skcol];
  unsigned short* BsW = &Bs[srow * 32 + skcol];
  const unsigned short* Ag = A + (long)(m0 + srow) * K + skcol;
  const unsigned short* Bg = B + (long)(n0 + srow) * K + skcol;

  const int fr = lane & 15, fk = (lane >> 4) * 8;

  for (int k0 = 0; k0 < K; k0 += 32) {
    gl2lds16(AsW,            Ag + k0);
    gl2lds16(AsW + 16 * 32,  Ag + (long)16 * K + k0);
    gl2lds16(BsW,            Bg + k0);
    gl2lds16(BsW + 16 * 32,  Bg + (long)16 * K + k0);
    __syncthreads();
    short8 af[4], bf[4];
    #pragma unroll
    for (int i = 0; i < 4; i++) {
      af[i] = *(const short8*)&As[(wm + i * 16 + fr) * 32 + fk];
      bf[i] = *(const short8*)&Bs[(wn + i * 16 + fr) * 32 + fk];
    }
    #pragma unroll
    for (int i = 0; i < 4; i++)
      #pragma unroll
      for (int j = 0; j < 4; j++)
        acc[i][j] = __builtin_amdgcn_mfma_f32_16x16x32_bf16(af[i], bf[j], acc[i][j], 0, 0, 0);
    __syncthreads();
  }

  const int cl = lane & 15, rq = (lane >> 4) * 4;
  #pragma unroll
  for (int i = 0; i < 4; i++)
    #pragma unroll
    for (int j = 0; j < 4; j++) {
      int col = n0 + wn + j * 16 + cl;
      #pragma unroll
      for (int r = 0; r < 4; r++) {
        int row = m0 + wm + i * 16 + rq + r;
        float v = acc[i][j][r];
        if (col < 512) OutU[(long)row * 512 + col] = f2b(v);
        else           OutZ[(long)row * 512 + (col - 512)] = f2b(v);
      }
    }
}

// ---------------- 64x128 bf16 MFMA GEMM for out_proj (more blocks/CU) ------
// OutF[row*N+col] = Xres[row*N+col] + (mask[row] ? acc : 0)
__global__ __launch_bounds__(256) void gemm64(
    const unsigned short* __restrict__ A, const unsigned short* __restrict__ B,
    const float* __restrict__ Xres, float* __restrict__ OutF,
    const int* __restrict__ mask, int N, int K) {
  __shared__ unsigned short As[64 * 32];
  __shared__ unsigned short Bs[128 * 32];
  const int tid = threadIdx.x;
  const int wave = tid >> 6, lane = tid & 63;
  const int m0 = blockIdx.x * 64, n0 = blockIdx.y * 128;
  const int wm = (wave >> 1) * 32, wn = (wave & 1) * 64;

  f32x4 acc[2][4];
  #pragma unroll
  for (int i = 0; i < 2; i++)
    #pragma unroll
    for (int j = 0; j < 4; j++)
      #pragma unroll
      for (int r = 0; r < 4; r++) acc[i][j][r] = 0.f;

  const int srow = wave * 32 + (lane >> 2);
  const int skcol = (lane & 3) * 8;
  unsigned short* AsW = &As[srow * 32 + skcol];     // valid for wave<2
  unsigned short* BsW = &Bs[srow * 32 + skcol];
  const unsigned short* Ag = A + (long)(m0 + srow) * K + skcol;
  const unsigned short* Bg = B + (long)(n0 + srow) * K + skcol;

  const int fr = lane & 15, fk = (lane >> 4) * 8;

  for (int k0 = 0; k0 < K; k0 += 32) {
    if (wave < 2) {
      gl2lds16(AsW,            Ag + k0);
      gl2lds16(AsW + 16 * 32,  Ag + (long)16 * K + k0);
    }
    gl2lds16(BsW,            Bg + k0);
    gl2lds16(BsW + 16 * 32,  Bg + (long)16 * K + k0);
    __syncthreads();
    short8 af[2], bf[4];
    #pragma unroll
    for (int i = 0; i < 2; i++)
      af[i] = *(const short8*)&As[(wm + i * 16 + fr) * 32 + fk];
    #pragma unroll
    for (int j = 0; j < 4; j++)
      bf[j] = *(const short8*)&Bs[(wn + j * 16 + fr) * 32 + fk];
    #pragma unroll
    for (int i = 0; i < 2; i++)
      #pragma unroll
      for (int j = 0; j < 4; j++)
        acc[i][j] = __builtin_amdgcn_mfma_f32_16x16x32_bf16(af[i], bf[j], acc[i][j], 0, 0, 0);
    __syncthreads();
  }

  const int cl = lane & 15, rq = (lane >> 4) * 4;
  #pragma unroll
  for (int i = 0; i < 2; i++)
    #pragma unroll
    for (int j = 0; j < 4; j++) {
      int col = n0 + wn + j * 16 + cl;
      #pragma unroll
      for (int r = 0; r < 4; r++) {
        int row = m0 + wm + i * 16 + rq + r;
        long idx = (long)row * N + col;
        OutF[idx] = Xres[idx] + (mask[row] ? acc[i][j][r] : 0.f);
      }
    }
}

// ---------------- 128x48 bf16 MFMA GEMM for x_proj (K=512), fp32 out -------
__global__ __launch_bounds__(256) void gemm_n48(
    const unsigned short* __restrict__ A, const unsigned short* __restrict__ B,
    float* __restrict__ Out, int K) {
  __shared__ unsigned short As[128 * 32];
  __shared__ unsigned short Bs[48 * 32];
  const int tid = threadIdx.x;
  const int wave = tid >> 6, lane = tid & 63;
  const int m0 = blockIdx.x * 128;
  const int wm = wave * 32;

  f32x4 acc[2][3];
  #pragma unroll
  for (int i = 0; i < 2; i++)
    #pragma unroll
    for (int j = 0; j < 3; j++)
      #pragma unroll
      for (int r = 0; r < 4; r++) acc[i][j][r] = 0.f;

  const int srow = wave * 32 + (lane >> 2);
  const int skcol = (lane & 3) * 8;
  unsigned short* AsW = &As[srow * 32 + skcol];
  const unsigned short* Ag = A + (long)(m0 + srow) * K + skcol;
  const int brow = wave * 16 + (lane >> 2);   // waves 0..2 stage rows 0..47
  unsigned short* BsW = &Bs[brow * 32 + skcol];
  const unsigned short* Bg = B + (long)brow * K + skcol;

  const int fr = lane & 15, fk = (lane >> 4) * 8;

  for (int k0 = 0; k0 < K; k0 += 32) {
    gl2lds16(AsW,           Ag + k0);
    gl2lds16(AsW + 16 * 32, Ag + (long)16 * K + k0);
    if (wave < 3) gl2lds16(BsW, Bg + k0);
    __syncthreads();
    short8 af[2], bf[3];
    #pragma unroll
    for (int i = 0; i < 2; i++)
      af[i] = *(const short8*)&As[(wm + i * 16 + fr) * 32 + fk];
    #pragma unroll
    for (int j = 0; j < 3; j++)
      bf[j] = *(const short8*)&Bs[(j * 16 + fr) * 32 + fk];
    #pragma unroll
    for (int i = 0; i < 2; i++)
      #pragma unroll
      for (int j = 0; j < 3; j++)
        acc[i][j] = __builtin_amdgcn_mfma_f32_16x16x32_bf16(af[i], bf[j], acc[i][j], 0, 0, 0);
    __syncthreads();
  }

  const int cl = lane & 15, rq = (lane >> 4) * 4;
  #pragma unroll
  for (int i = 0; i < 2; i++)
    #pragma unroll
    for (int j = 0; j < 3; j++) {
      int col = j * 16 + cl;
      #pragma unroll
      for (int r = 0; r < 4; r++) {
        int row = m0 + wm + i * 16 + rq + r;
        Out[(long)row * 48 + col] = acc[i][j][r];
      }
    }
}

// ---------------- causal depthwise conv(4) + silu, 8 d per thread ----------
__global__ __launch_bounds__(256, 4) void conv_silu(
    const unsigned short* __restrict__ Upre, const float* __restrict__ cw,
    const float* __restrict__ cb, unsigned short* __restrict__ U) {
  int gid = blockIdx.x * 256 + threadIdx.x;
  int d8 = gid & 63;
  int row = gid >> 6;          // b*2048 + t (chunk-local)
  int t = row & 2047;
  int d0 = d8 * 8;
  f32x4 cwv[8];
  #pragma unroll
  for (int di = 0; di < 8; di++) cwv[di] = ((const f32x4*)(cw + (d0 + di) * 4))[0];
  f32x4 cbv0 = ((const f32x4*)(cb + d0))[0];
  f32x4 cbv1 = ((const f32x4*)(cb + d0))[1];
  float acc[8] = {cbv0.x, cbv0.y, cbv0.z, cbv0.w, cbv1.x, cbv1.y, cbv1.z, cbv1.w};
  #pragma unroll
  for (int k = 0; k < 4; k++) {
    int tt = t + k - 3;
    if (tt >= 0) {          // wave-uniform branch
      ush8 uv = *(const ush8*)(Upre + (long)(row + k - 3) * 512 + d0);
      #pragma unroll
      for (int di = 0; di < 8; di++)
        acc[di] = fmaf(b2f(uv[di]), cwv[di][k], acc[di]);
    }
  }
  ush8 o;
  #pragma unroll
  for (int di = 0; di < 8; di++) {
    float sg = 1.f / (1.f + __expf(-acc[di]));
    o[di] = f2b(acc[di] * sg);
  }
  *(ush8*)(U + (long)row * 512 + d0) = o;
}

// ---------------- scan pass 1: per-chunk end state + sum(dt) ---------------
__global__ __launch_bounds__(256, 4) void scan_p1(
    const unsigned short* __restrict__ U, const float* __restrict__ XD,
    const float* __restrict__ AA, const float* __restrict__ dtw,
    const float* __restrict__ dtb, float* __restrict__ HCH,
    float* __restrict__ DTS) {
  int gid = blockIdx.x * 256 + threadIdx.x;
  int d = gid & 511;
  int bc = gid >> 9;
  int c = bc & 63, b = bc >> 6;
  // opaque loads: values must live in VGPRs (no remat from global in the loop)
  f32x4 aa0 = ld4(AA + d * 16),      aa1 = ld4(AA + d * 16 + 4),
        aa2 = ld4(AA + d * 16 + 8),  aa3 = ld4(AA + d * 16 + 12);
  f32x4 w0 = ld4(dtw + d * 16),      w1 = ld4(dtw + d * 16 + 4),
        w2 = ld4(dtw + d * 16 + 8),  w3 = ld4(dtw + d * 16 + 12);
  asm volatile("s_waitcnt vmcnt(0)"
               : "+v"(aa0), "+v"(aa1), "+v"(aa2), "+v"(aa3),
                 "+v"(w0), "+v"(w1), "+v"(w2), "+v"(w3));
  f32x4 h0 = {0.f,0.f,0.f,0.f}, h1 = h0, h2 = h0, h3 = h0;
  float bias = dtb[d];
  float dts = 0.f;
  int row = b * 2048 + c * 32;
  const unsigned short* Up = U + (long)row * 512 + d;
  for (int tt = 0; tt < 32; tt++, row++, Up += 512) {
    // XD row is wave-uniform: force scalar loads
    int off = __builtin_amdgcn_readfirstlane(row * 48);
    const f32x4* xs = (const f32x4*)(XD + off);
    f32x4 x0 = xs[0], x1 = xs[1], x2 = xs[2], x3 = xs[3];   // dt_in
    f32x4 B0 = xs[4], B1 = xs[5], B2 = xs[6], B3 = xs[7];   // B
    f32x4 pp = x0 * w0 + x1 * w1 + x2 * w2 + x3 * w3;
    float s = bias + pp.x + pp.y + pp.z + pp.w;
    float e = __expf(-fabsf(s));
    float dt = fmaxf(s, 0.f) + __logf(1.f + e);   // softplus
    float du = dt * b2f(*Up);
    h0 = exp2v(dt * aa0) * h0 + du * B0;
    h1 = exp2v(dt * aa1) * h1 + du * B1;
    h2 = exp2v(dt * aa2) * h2 + du * B2;
    h3 = exp2v(dt * aa3) * h3 + du * B3;
    dts += dt;
  }
  f32x4* hp = (f32x4*)(HCH + (long)gid * 16);
  hp[0] = h0; hp[1] = h1; hp[2] = h2; hp[3] = h3;
  DTS[gid] = dts;
}

// ---------------- scan pass 2: prefix over chunks (h_end -> h_start) -------
__global__ __launch_bounds__(256) void scan_p2(
    float* __restrict__ HCH, const float* __restrict__ DTS,
    const float* __restrict__ AA) {
  int gid = blockIdx.x * 256 + threadIdx.x;   // b*8192 + d*16 + n
  int n = gid & 15;
  int d = (gid >> 4) & 511;
  int b = gid >> 13;
  float aa = AA[d * 16 + n];
  float hrun = 0.f;
  for (int c = 0; c < 64; c++) {
    long base = ((long)b * 64 + c) * 512 + d;
    long idx = base * 16 + n;
    float hend = HCH[idx];
    float P = ex2(DTS[base] * aa);
    HCH[idx] = hrun;            // becomes h_start for chunk c
    hrun = fmaf(P, hrun, hend);
  }
}

// ---------------- scan pass 3: replay with h_start, fused gate -------------
// Y may alias U (same-thread same-element read-before-write)
__global__ __launch_bounds__(256, 4) void scan_p3(
    const unsigned short* __restrict__ U, const unsigned short* __restrict__ Z,
    const float* __restrict__ XD, const float* __restrict__ AA,
    const float* __restrict__ dtw, const float* __restrict__ dtb,
    const float* __restrict__ HCH, const float* __restrict__ skD,
    unsigned short* __restrict__ Y) {
  int gid = blockIdx.x * 256 + threadIdx.x;
  int d = gid & 511;
  int bc = gid >> 9;
  int c = bc & 63, b = bc >> 6;
  f32x4 aa0 = ld4(AA + d * 16),      aa1 = ld4(AA + d * 16 + 4),
        aa2 = ld4(AA + d * 16 + 8),  aa3 = ld4(AA + d * 16 + 12);
  f32x4 w0 = ld4(dtw + d * 16),      w1 = ld4(dtw + d * 16 + 4),
        w2 = ld4(dtw + d * 16 + 8),  w3 = ld4(dtw + d * 16 + 12);
  asm volatile("s_waitcnt vmcnt(0)"
               : "+v"(aa0), "+v"(aa1), "+v"(aa2), "+v"(aa3),
                 "+v"(w0), "+v"(w1), "+v"(w2), "+v"(w3));
  const f32x4* hp = (const f32x4*)(HCH + (long)gid * 16);
  f32x4 h0 = hp[0], h1 = hp[1], h2 = hp[2], h3 = hp[3];
  float bias = dtb[d];
  float sD = skD[d];
  int row = b * 2048 + c * 32;
  const unsigned short* Up = U + (long)row * 512 + d;
  const unsigned short* Zp = Z + (long)row * 512 + d;
  unsigned short* Yp = Y + (long)row * 512 + d;
  for (int tt = 0; tt < 32; tt++, row++, Up += 512, Zp += 512, Yp += 512) {
    int off = __builtin_amdgcn_readfirstlane(row * 48);
    const f32x4* xs = (const f32x4*)(XD + off);
    f32x4 x0 = xs[0], x1 = xs[1], x2 = xs[2], x3 = xs[3];   // dt_in
    f32x4 B0 = xs[4], B1 = xs[5], B2 = xs[6], B3 = xs[7];   // B
    f32x4 C0 = xs[8], C1 = xs[9], C2 = xs[10], C3 = xs[11]; // C
    f32x4 pp = x0 * w0 + x1 * w1 + x2 * w2 + x3 * w3;
    float s = bias + pp.x + pp.y + pp.z + pp.w;
    float e = __expf(-fabsf(s));
    float dt = fmaxf(s, 0.f) + __logf(1.f + e);
    float u = b2f(*Up);
    float du = dt * u;
    h0 = exp2v(dt * aa0) * h0 + du * B0;
    h1 = exp2v(dt * aa1) * h1 + du * B1;
    h2 = exp2v(dt * aa2) * h2 + du * B2;
    h3 = exp2v(dt * aa3) * h3 + du * B3;
    f32x4 yv = h0 * C0 + h1 * C1 + h2 * C2 + h3 * C3;
    float y = yv.x + yv.y + yv.z + yv.w + u * sD;
    float z = b2f(*Zp);
    float sg = z / (1.f + __expf(-z));      // silu(z)
    *Yp = f2b(y * sg);
  }
}

extern "C" void kernel_launch(void* const* d_in, const int* in_sizes, int n_in,
                              void* d_out, int out_size, void* d_ws, size_t ws_size,
                              hipStream_t stream) {
  const float* x        = (const float*)d_in[0];
  const int*   mask     = (const int*)d_in[1];
  const float* ln_w     = (const float*)d_in[2];
  const float* ln_b     = (const float*)d_in[3];
  const float* in_proj  = (const float*)d_in[4];
  const float* conv_w   = (const float*)d_in[5];
  const float* conv_b   = (const float*)d_in[6];
  const float* x_proj   = (const float*)d_in[7];
  const float* dt_w     = (const float*)d_in[8];
  const float* dt_b     = (const float*)d_in[9];
  const float* A_log    = (const float*)d_in[10];
  const float* skip_D   = (const float*)d_in[11];
  const float* out_proj = (const float*)d_in[12];
  float* X = (float*)d_out;

  // ---- workspace layout (~114 MB total) ----
  char* p = (char*)d_ws;
  auto alloc = [&](size_t n) { char* r = p; p += (n + 255) & ~(size_t)255; return r; };
  unsigned short* WBin  = (unsigned short*)alloc((size_t)2 * 1024 * 256 * 2);  // 1 MB
  unsigned short* WBx   = (unsigned short*)alloc((size_t)2 * 48 * 512 * 2);
  unsigned short* WBout = (unsigned short*)alloc((size_t)2 * 256 * 512 * 2);
  float*          AA    = (float*)alloc((size_t)2 * 512 * 16 * 4);
  char* R_XN   = alloc((size_t)RC * 256 * 2);        // 16 MB: XN, then XD+DTS
  char* R_UPRE = alloc((size_t)RC * 512 * 2);        // 32 MB: Upre, then HCH
  char* R_Z    = alloc((size_t)RC * 512 * 2);        // 32 MB: Z
  char* R_U    = alloc((size_t)RC * 512 * 2);        // 32 MB: U (=Y in-place)

  unsigned short* XN   = (unsigned short*)R_XN;
  float*          XD   = (float*)R_XN;                         // after in_proj
  float*          DTS  = (float*)(R_XN + 8388608);             // 2 MB @ +8 MB
  unsigned short* Upre = (unsigned short*)R_UPRE;
  float*          HCH  = (float*)R_UPRE;                       // after conv
  unsigned short* Z    = (unsigned short*)R_Z;
  unsigned short* U    = (unsigned short*)R_U;

  prep_weights<<<3328, 256, 0, stream>>>(in_proj, x_proj, out_proj, A_log,
                                         WBin, WBx, WBout, AA);
  mask_x<<<65536, 256, 0, stream>>>(x, mask, X);

  for (int ch = 0; ch < 2; ch++) {
    const long row0 = (long)ch * RC;
    float* Xc = X + row0 * 256;
    const int* maskc = mask + row0;
    for (int i = 0; i < 2; i++) {
      ln_fwd<<<RC / 4, 256, 0, stream>>>(Xc, ln_w + i * 256, ln_b + i * 256, XN);
      gemm128<<<dim3(RC / 128, 8), 256, 0, stream>>>(XN, WBin + i * 262144,
          Upre, Z, 1024, 256);
      conv_silu<<<RC / 4, 256, 0, stream>>>(Upre, conv_w + i * 2048,
          conv_b + i * 512, U);
      gemm_n48<<<RC / 128, 256, 0, stream>>>(U, WBx + i * 24576, XD, 512);
      scan_p1<<<BCH * 128, 256, 0, stream>>>(U, XD, AA + i * 8192,
          dt_w + i * 8192, dt_b + i * 512, HCH, DTS);
      scan_p2<<<BCH * 32, 256, 0, stream>>>(HCH, DTS, AA + i * 8192);
      scan_p3<<<BCH * 128, 256, 0, stream>>>(U, Z, XD, AA + i * 8192,
          dt_w + i * 8192, dt_b + i * 512, HCH, skip_D + i * 512, U);
      gemm64<<<dim3(RC / 64, 2), 256, 0, stream>>>(U, WBout + i * 131072,
          Xc, Xc, maskc, 256, 512);
    }
  }
}